// Round 1
// baseline (2782.400 us; speedup 1.0000x reference)
//
#include <hip/hip_runtime.h>
#include <hip/hip_bf16.h>
#include <math.h>

#define B_ 4
#define S_ 4096
#define H_ 1024
#define D_ 64
#define M_ (B_*S_)            // 16384 rows
#define NEGINF (-1.0e12f)

// workspace layout (float offsets)
#define WS_K   0
#define WS_Q   (M_*D_)                    // 1048576
#define WS_V   (2*M_*D_)
#define WS_PA  (3*M_*D_)                  // 512 blocks * 64 rows * 64 d
#define WS_PM  (WS_PA + 512*64*64)
#define WS_PL  (WS_PM + 512*64)

// ---------------------------------------------------------------------------
// Kernel 1: fused QKV projection.  K/Q/V[m][d] = x[m][:] . W*[d][:]
// Tiling: BM=64 rows, N=192 (all three heads), BK=16.  256 threads (16x16),
// thread tile 4 rows x 12 cols.  Register-prefetch of next K-slab.
// ---------------------------------------------------------------------------
__global__ __launch_bounds__(256, 1)
void qkv_proj(const float* __restrict__ x, const float* __restrict__ Wk,
              const float* __restrict__ Wq, const float* __restrict__ Wv,
              float* __restrict__ ws)
{
    __shared__ float xs[16][68];     // [k][m] transposed
    __shared__ float wsm[16][196];   // [k][n] transposed, n<64:K 64..127:Q 128..191:V
    const int tid = threadIdx.x;
    const int ty = tid >> 4, tx = tid & 15;
    const int m0 = blockIdx.x * 64;
    float* Kb = ws + WS_K; float* Qb = ws + WS_Q; float* Vb = ws + WS_V;

    const int xrow = tid >> 2, xkq = (tid & 3) * 4;   // x stage mapping

    float acc[4][12];
    #pragma unroll
    for (int r = 0; r < 4; ++r)
        #pragma unroll
        for (int c = 0; c < 12; ++c) acc[r][c] = 0.f;

    // prefetch slab k0=0
    float4 xg, wg[3];
    {
        xg = *(const float4*)(x + (size_t)(m0 + xrow) * H_ + xkq);
        #pragma unroll
        for (int q = 0; q < 3; ++q) {
            int idx = tid + 256*q;
            int n = idx >> 2, kq = (idx & 3) * 4;
            const float* wp = (n < 64) ? (Wk + (size_t)n*H_)
                             : (n < 128 ? (Wq + (size_t)(n-64)*H_)
                                        : (Wv + (size_t)(n-128)*H_));
            wg[q] = *(const float4*)(wp + kq);
        }
    }

    for (int k0 = 0; k0 < H_; k0 += 16) {
        __syncthreads();    // previous compute done reading LDS
        // commit prefetched regs to LDS (transposed)
        xs[xkq+0][xrow] = xg.x; xs[xkq+1][xrow] = xg.y;
        xs[xkq+2][xrow] = xg.z; xs[xkq+3][xrow] = xg.w;
        #pragma unroll
        for (int q = 0; q < 3; ++q) {
            int idx = tid + 256*q;
            int n = idx >> 2, kq = (idx & 3) * 4;
            wsm[kq+0][n] = wg[q].x; wsm[kq+1][n] = wg[q].y;
            wsm[kq+2][n] = wg[q].z; wsm[kq+3][n] = wg[q].w;
        }
        // issue next slab's global loads (hidden under compute)
        int kn = (k0 + 16 < H_) ? k0 + 16 : 0;
        xg = *(const float4*)(x + (size_t)(m0 + xrow) * H_ + kn + xkq);
        #pragma unroll
        for (int q = 0; q < 3; ++q) {
            int idx = tid + 256*q;
            int n = idx >> 2, kq = (idx & 3) * 4;
            const float* wp = (n < 64) ? (Wk + (size_t)n*H_)
                             : (n < 128 ? (Wq + (size_t)(n-64)*H_)
                                        : (Wv + (size_t)(n-128)*H_));
            wg[q] = *(const float4*)(wp + kn + kq);
        }
        __syncthreads();    // staging visible
        #pragma unroll
        for (int k = 0; k < 16; ++k) {
            const float4 xa = *(const float4*)&xs[k][ty*4];
            const float4 w0 = *(const float4*)&wsm[k][tx*12];
            const float4 w1 = *(const float4*)&wsm[k][tx*12+4];
            const float4 w2 = *(const float4*)&wsm[k][tx*12+8];
            float ar[4] = {xa.x, xa.y, xa.z, xa.w};
            float wv[12] = {w0.x,w0.y,w0.z,w0.w, w1.x,w1.y,w1.z,w1.w, w2.x,w2.y,w2.z,w2.w};
            #pragma unroll
            for (int r = 0; r < 4; ++r)
                #pragma unroll
                for (int c = 0; c < 12; ++c)
                    acc[r][c] = fmaf(ar[r], wv[c], acc[r][c]);
        }
    }

    // epilogue: scatter to K/Q/V arrays
    #pragma unroll
    for (int r = 0; r < 4; ++r) {
        const size_t m = m0 + ty*4 + r;
        #pragma unroll
        for (int c = 0; c < 12; ++c) {
            int col = tx*12 + c;
            float* o = (col < 64) ? Kb : (col < 128 ? Qb : Vb);
            o[m*D_ + (col & 63)] = acc[r][c];
        }
    }
}

// ---------------------------------------------------------------------------
// Kernel 2: flash attention (fp32 VALU).  Rows = K-projection (swapped attn),
// cols j = Q/V.  64-row tile, 64-col chunk, j-range split in 2 per row-tile
// (512 blocks -> all 256 CUs).  Writes unnormalized partial (acc, m, l).
// LDS exactly 64 KB: Kt,Qt (d-major transposed), Vs, Pt  each [64][64].
// ---------------------------------------------------------------------------
__global__ __launch_bounds__(256, 2)
void flash_fp32(const int* __restrict__ maskp, float* __restrict__ ws)
{
    __shared__ float Kt[64][64];   // [d][i]
    __shared__ float Qt[64][64];   // [d][j]
    __shared__ float Vs[64][64];   // [j][d]
    __shared__ float Pt[64][64];   // [j][i]

    const int tid = threadIdx.x;
    const int ty = tid >> 4, tx = tid & 15;
    const int bx = blockIdx.x;
    const int jh = bx & 1, it = (bx >> 1) & 63, b = bx >> 7;
    const int i0 = it * 64;
    const size_t base = (size_t)b * S_ * D_;
    const int jbase = jh * (S_/2), jend = jbase + (S_/2);

    const float* Kb = ws + WS_K; const float* Qb = ws + WS_Q; const float* Vb = ws + WS_V;
    const float scale = 0.125f;   // 1/sqrt(64)

    // stage K tile transposed (visible after first in-loop barrier)
    #pragma unroll
    for (int q = 0; q < 4; ++q) {
        int idx = tid + 256*q;
        int i = idx >> 4, dd = (idx & 15) * 4;
        float4 g = *(const float4*)(Kb + base + (size_t)(i0 + i)*D_ + dd);
        Kt[dd+0][i] = g.x; Kt[dd+1][i] = g.y; Kt[dd+2][i] = g.z; Kt[dd+3][i] = g.w;
    }

    float4 qg[4], vg[4];
    auto preload = [&](int jc) {
        #pragma unroll
        for (int q = 0; q < 4; ++q) {
            int idx = tid + 256*q;
            int j = idx >> 4, dd = (idx & 15) * 4;
            qg[q] = *(const float4*)(Qb + base + (size_t)(jc + j)*D_ + dd);
            vg[q] = *(const float4*)(Vb + base + (size_t)(jc + j)*D_ + dd);
        }
    };
    preload(jbase);

    float acc[4][4], mi[4], li[4];
    #pragma unroll
    for (int r = 0; r < 4; ++r) {
        mi[r] = -INFINITY; li[r] = 0.f;
        #pragma unroll
        for (int c = 0; c < 4; ++c) acc[r][c] = 0.f;
    }

    for (int jc = jbase; jc < jend; jc += 64) {
        __syncthreads();   // (a) prior PV done; Kt visible on first iter
        #pragma unroll
        for (int q = 0; q < 4; ++q) {
            int idx = tid + 256*q;
            int j = idx >> 4, dd = (idx & 15) * 4;
            Qt[dd+0][j] = qg[q].x; Qt[dd+1][j] = qg[q].y;
            Qt[dd+2][j] = qg[q].z; Qt[dd+3][j] = qg[q].w;
            *(float4*)&Vs[j][dd] = vg[q];
        }
        // issue next chunk's loads; consumed after next (a)
        int jn = jc + 64; if (jn >= jend) jn = jbase;
        preload(jn);
        // mask flags for this thread's 4 columns (replace semantics)
        float on[4];
        #pragma unroll
        for (int c = 0; c < 4; ++c)
            on[c] = (maskp[b*S_ + jc + tx*4 + c] != 0) ? 1.f : 0.f;
        __syncthreads();   // (b) staging visible

        // QK^T: s[r][c] = K[i0+ty4+r] . Q[jc+tx4+c]
        float s[4][4];
        #pragma unroll
        for (int r = 0; r < 4; ++r)
            #pragma unroll
            for (int c = 0; c < 4; ++c) s[r][c] = 0.f;
        #pragma unroll
        for (int d = 0; d < 64; ++d) {
            const float4 ka = *(const float4*)&Kt[d][ty*4];
            const float4 qv = *(const float4*)&Qt[d][tx*4];
            float ar[4] = {ka.x, ka.y, ka.z, ka.w};
            float qc[4] = {qv.x, qv.y, qv.z, qv.w};
            #pragma unroll
            for (int r = 0; r < 4; ++r)
                #pragma unroll
                for (int c = 0; c < 4; ++c)
                    s[r][c] = fmaf(ar[r], qc[c], s[r][c]);
        }

        // online softmax (rows reduce over the 16 tx lanes; lane bits 0..3)
        float p[4][4];
        #pragma unroll
        for (int r = 0; r < 4; ++r) {
            float rm = NEGINF;
            #pragma unroll
            for (int c = 0; c < 4; ++c) {
                float sv = (on[c] > 0.f) ? s[r][c]*scale : NEGINF;
                s[r][c] = sv;
                rm = fmaxf(rm, sv);
            }
            rm = fmaxf(rm, __shfl_xor(rm, 1));
            rm = fmaxf(rm, __shfl_xor(rm, 2));
            rm = fmaxf(rm, __shfl_xor(rm, 4));
            rm = fmaxf(rm, __shfl_xor(rm, 8));
            const float mnew = fmaxf(mi[r], rm);
            const float alpha = __expf(mi[r] - mnew);  // exp(-inf)=0 first time
            float sum = 0.f;
            #pragma unroll
            for (int c = 0; c < 4; ++c) {
                p[r][c] = __expf(s[r][c] - mnew);      // all-masked prefix -> exp(0)=1
                sum += p[r][c];
            }
            sum += __shfl_xor(sum, 1);
            sum += __shfl_xor(sum, 2);
            sum += __shfl_xor(sum, 4);
            sum += __shfl_xor(sum, 8);
            li[r] = li[r]*alpha + sum;
            mi[r] = mnew;
            #pragma unroll
            for (int c = 0; c < 4; ++c) acc[r][c] *= alpha;
        }
        // stage P transposed [j][i]
        #pragma unroll
        for (int c = 0; c < 4; ++c)
            *(float4*)&Pt[tx*4+c][ty*4] = make_float4(p[0][c], p[1][c], p[2][c], p[3][c]);
        __syncthreads();   // (c) P visible

        // PV: acc[r][c] += sum_j P[j][i] * V[j][d]
        #pragma unroll
        for (int j = 0; j < 64; ++j) {
            const float4 pa = *(const float4*)&Pt[j][ty*4];
            const float4 vv = *(const float4*)&Vs[j][tx*4];
            float pr[4] = {pa.x, pa.y, pa.z, pa.w};
            float vc[4] = {vv.x, vv.y, vv.z, vv.w};
            #pragma unroll
            for (int r = 0; r < 4; ++r)
                #pragma unroll
                for (int c = 0; c < 4; ++c)
                    acc[r][c] = fmaf(pr[r], vc[c], acc[r][c]);
        }
    }

    // write partials (unnormalized)
    float* pacc = ws + WS_PA + (size_t)bx * 4096;
    float* pm   = ws + WS_PM + bx * 64;
    float* pl   = ws + WS_PL + bx * 64;
    #pragma unroll
    for (int r = 0; r < 4; ++r)
        *(float4*)(pacc + (ty*4 + r)*64 + tx*4) =
            make_float4(acc[r][0], acc[r][1], acc[r][2], acc[r][3]);
    if (tx == 0) {
        #pragma unroll
        for (int r = 0; r < 4; ++r) { pm[ty*4+r] = mi[r]; pl[ty*4+r] = li[r]; }
    }
}

// ---------------------------------------------------------------------------
// Kernel 3: combine the two j-half partials per row and normalize.
// ---------------------------------------------------------------------------
__global__ __launch_bounds__(256)
void combine(const float* __restrict__ ws, float* __restrict__ out)
{
    const int gid = blockIdx.x * 256 + threadIdx.x;   // 0 .. 262143
    const int row = gid >> 4, q = gid & 15;
    const int b = row >> 12, it = (row >> 6) & 63, il = row & 63;
    const int pb0 = (b << 7) | (it << 1);
    const float* pacc = ws + WS_PA;
    const float* pm   = ws + WS_PM;
    const float* pl   = ws + WS_PL;
    const float m0 = pm[pb0*64 + il],     m1 = pm[(pb0+1)*64 + il];
    const float l0 = pl[pb0*64 + il],     l1 = pl[(pb0+1)*64 + il];
    const float M  = fmaxf(m0, m1);
    const float w0 = __expf(m0 - M), w1 = __expf(m1 - M);
    const float inv = 1.0f / (l0*w0 + l1*w1);
    const float4 a0 = *(const float4*)(pacc + (size_t)pb0*4096 + il*64 + q*4);
    const float4 a1 = *(const float4*)(pacc + (size_t)(pb0+1)*4096 + il*64 + q*4);
    float4 o;
    o.x = (a0.x*w0 + a1.x*w1) * inv;
    o.y = (a0.y*w0 + a1.y*w1) * inv;
    o.z = (a0.z*w0 + a1.z*w1) * inv;
    o.w = (a0.w*w0 + a1.w*w1) * inv;
    *(float4*)(out + (size_t)row*64 + q*4) = o;
}

// ---------------------------------------------------------------------------
extern "C" void kernel_launch(void* const* d_in, const int* in_sizes, int n_in,
                              void* d_out, int out_size, void* d_ws, size_t ws_size,
                              hipStream_t stream) {
    const float* x    = (const float*)d_in[0];
    const int*   mask = (const int*)d_in[1];
    const float* Wk   = (const float*)d_in[2];
    const float* Wq   = (const float*)d_in[3];
    const float* Wv   = (const float*)d_in[4];
    float* out = (float*)d_out;
    float* ws  = (float*)d_ws;

    hipLaunchKernelGGL(qkv_proj,   dim3(M_/64), dim3(256), 0, stream, x, Wk, Wq, Wv, ws);
    hipLaunchKernelGGL(flash_fp32, dim3(512),   dim3(256), 0, stream, mask, ws);
    hipLaunchKernelGGL(combine,    dim3(1024),  dim3(256), 0, stream, ws, out);
}

// Round 2
// 310.723 us; speedup vs baseline: 8.9546x; 8.9546x over previous
//
#include <hip/hip_runtime.h>
#include <hip/hip_bf16.h>
#include <math.h>

#define B_ 4
#define S_ 4096
#define H_ 1024
#define D_ 64
#define M_ (B_*S_)            // 16384 rows
#define NEGINF (-1.0e12f)

typedef __attribute__((ext_vector_type(8))) short bf16x8;
typedef __attribute__((ext_vector_type(8))) unsigned short u16x8;
typedef __attribute__((ext_vector_type(4))) float f32x4;

// ---- workspace byte offsets ----
#define OFF_KH   (0)                       // short [16384][64]
#define OFF_KL   (2*1024*1024)
#define OFF_QH   (4*1024*1024)
#define OFF_QL   (6*1024*1024)
#define OFF_VTH  (8*1024*1024)             // short [64][16384]  (V transposed)
#define OFF_VTL  (10*1024*1024)
#define OFF_PACC (12*1024*1024)            // float [512][4096]
#define OFF_PM   (20*1024*1024)            // float [512][64]
#define OFF_PL2  (20*1024*1024 + 131072)   // float [512][64]
// float-index versions for combine
#define PACC_F 3145728
#define PM_F   5242880
#define PL_F   5275648

__device__ __forceinline__ unsigned short f2bf(float f) {
    union { float f; unsigned u; } v; v.f = f;
    unsigned r = (v.u + 0x7fffu + ((v.u >> 16) & 1u)) >> 16;
    return (unsigned short)r;
}
__device__ __forceinline__ float bf2f(unsigned short h) {
    union { unsigned u; float f; } v; v.u = ((unsigned)h) << 16;
    return v.f;
}

// ---------------------------------------------------------------------------
// Kernel 1: fused QKV projection (fp32 VALU — worked in R1).
// New epilogue: emit bf16 hi/lo splits; V is emitted TRANSPOSED [d][m].
// ---------------------------------------------------------------------------
__global__ __launch_bounds__(256, 1)
void qkv_proj(const float* __restrict__ x, const float* __restrict__ Wk,
              const float* __restrict__ Wq, const float* __restrict__ Wv,
              char* __restrict__ wsb)
{
    __shared__ float xs[16][68];     // [k][m] transposed
    __shared__ float wsm[16][196];   // [k][n] transposed, n<64:K 64..127:Q 128..191:V
    const int tid = threadIdx.x;
    const int ty = tid >> 4, tx = tid & 15;
    const int m0 = blockIdx.x * 64;

    short* Khg = (short*)(wsb + OFF_KH);
    short* Klg = (short*)(wsb + OFF_KL);
    short* Qhg = (short*)(wsb + OFF_QH);
    short* Qlg = (short*)(wsb + OFF_QL);
    short* Vthg = (short*)(wsb + OFF_VTH);
    short* Vtlg = (short*)(wsb + OFF_VTL);

    const int xrow = tid >> 2, xkq = (tid & 3) * 4;

    float acc[4][12];
    #pragma unroll
    for (int r = 0; r < 4; ++r)
        #pragma unroll
        for (int c = 0; c < 12; ++c) acc[r][c] = 0.f;

    float4 xg, wg0, wg1, wg2;
    {
        xg = *(const float4*)(x + (size_t)(m0 + xrow) * H_ + xkq);
        {
            int idx = tid; int n = idx >> 2, kq = (idx & 3) * 4;
            const float* wp = (n < 64) ? (Wk + (size_t)n*H_)
                             : (n < 128 ? (Wq + (size_t)(n-64)*H_) : (Wv + (size_t)(n-128)*H_));
            wg0 = *(const float4*)(wp + kq);
        }
        {
            int idx = tid + 256; int n = idx >> 2, kq = (idx & 3) * 4;
            const float* wp = (n < 64) ? (Wk + (size_t)n*H_)
                             : (n < 128 ? (Wq + (size_t)(n-64)*H_) : (Wv + (size_t)(n-128)*H_));
            wg1 = *(const float4*)(wp + kq);
        }
        {
            int idx = tid + 512; int n = idx >> 2, kq = (idx & 3) * 4;
            const float* wp = (n < 64) ? (Wk + (size_t)n*H_)
                             : (n < 128 ? (Wq + (size_t)(n-64)*H_) : (Wv + (size_t)(n-128)*H_));
            wg2 = *(const float4*)(wp + kq);
        }
    }

    for (int k0 = 0; k0 < H_; k0 += 16) {
        __syncthreads();
        xs[xkq+0][xrow] = xg.x; xs[xkq+1][xrow] = xg.y;
        xs[xkq+2][xrow] = xg.z; xs[xkq+3][xrow] = xg.w;
        {
            int idx = tid; int n = idx >> 2, kq = (idx & 3) * 4;
            wsm[kq+0][n] = wg0.x; wsm[kq+1][n] = wg0.y; wsm[kq+2][n] = wg0.z; wsm[kq+3][n] = wg0.w;
        }
        {
            int idx = tid + 256; int n = idx >> 2, kq = (idx & 3) * 4;
            wsm[kq+0][n] = wg1.x; wsm[kq+1][n] = wg1.y; wsm[kq+2][n] = wg1.z; wsm[kq+3][n] = wg1.w;
        }
        {
            int idx = tid + 512; int n = idx >> 2, kq = (idx & 3) * 4;
            wsm[kq+0][n] = wg2.x; wsm[kq+1][n] = wg2.y; wsm[kq+2][n] = wg2.z; wsm[kq+3][n] = wg2.w;
        }
        int kn = (k0 + 16 < H_) ? k0 + 16 : 0;
        xg = *(const float4*)(x + (size_t)(m0 + xrow) * H_ + kn + xkq);
        {
            int idx = tid; int n = idx >> 2, kq = (idx & 3) * 4;
            const float* wp = (n < 64) ? (Wk + (size_t)n*H_)
                             : (n < 128 ? (Wq + (size_t)(n-64)*H_) : (Wv + (size_t)(n-128)*H_));
            wg0 = *(const float4*)(wp + kn + kq);
        }
        {
            int idx = tid + 256; int n = idx >> 2, kq = (idx & 3) * 4;
            const float* wp = (n < 64) ? (Wk + (size_t)n*H_)
                             : (n < 128 ? (Wq + (size_t)(n-64)*H_) : (Wv + (size_t)(n-128)*H_));
            wg1 = *(const float4*)(wp + kn + kq);
        }
        {
            int idx = tid + 512; int n = idx >> 2, kq = (idx & 3) * 4;
            const float* wp = (n < 64) ? (Wk + (size_t)n*H_)
                             : (n < 128 ? (Wq + (size_t)(n-64)*H_) : (Wv + (size_t)(n-128)*H_));
            wg2 = *(const float4*)(wp + kn + kq);
        }
        __syncthreads();
        #pragma unroll
        for (int k = 0; k < 16; ++k) {
            const float4 xa = *(const float4*)&xs[k][ty*4];
            const float4 w0 = *(const float4*)&wsm[k][tx*12];
            const float4 w1 = *(const float4*)&wsm[k][tx*12+4];
            const float4 w2 = *(const float4*)&wsm[k][tx*12+8];
            float ar[4] = {xa.x, xa.y, xa.z, xa.w};
            float wv[12] = {w0.x,w0.y,w0.z,w0.w, w1.x,w1.y,w1.z,w1.w, w2.x,w2.y,w2.z,w2.w};
            #pragma unroll
            for (int r = 0; r < 4; ++r)
                #pragma unroll
                for (int c = 0; c < 12; ++c)
                    acc[r][c] = fmaf(ar[r], wv[c], acc[r][c]);
        }
    }

    // epilogue: bf16 hi/lo split, V transposed
    #pragma unroll
    for (int r = 0; r < 4; ++r) {
        const size_t m = m0 + ty*4 + r;
        #pragma unroll
        for (int c = 0; c < 12; ++c) {
            int col = tx*12 + c;
            float v = acc[r][c];
            unsigned short hi = f2bf(v);
            unsigned short lo = f2bf(v - bf2f(hi));
            if (col < 64) {
                Khg[m*64 + col] = (short)hi; Klg[m*64 + col] = (short)lo;
            } else if (col < 128) {
                Qhg[m*64 + col - 64] = (short)hi; Qlg[m*64 + col - 64] = (short)lo;
            } else {
                int d = col - 128;
                Vthg[(size_t)d*M_ + m] = (short)hi; Vtlg[(size_t)d*M_ + m] = (short)lo;
            }
        }
    }
}

// ---------------------------------------------------------------------------
// Kernel 2: flash attention with split-bf16 MFMA (hh+hl+lh, ~fp32 accuracy).
// Block = 64 i-rows, 4 waves (16 rows each). Chunks of 64 j. j-split x2.
// LDS 48 KB: Qh/Ql [j][d], Vh/Vl [d][j], Ph/Pl per-wave [16][64], all
// XOR-swizzled (col ^= (row&7)<<3 in shorts) -> conflict-free b64/b128.
// ---------------------------------------------------------------------------
__global__ __launch_bounds__(256, 3)
void flash_mfma(const int* __restrict__ maskp, char* __restrict__ wsb)
{
    __shared__ short Qh[4096], Ql[4096];   // [j][d] swizzled
    __shared__ short Vh[4096], Vl[4096];   // [d][j] swizzled
    __shared__ short Ph[4][1024], Pl[4][1024];

    const short* __restrict__ Khg = (const short*)(wsb + OFF_KH);
    const short* __restrict__ Klg = (const short*)(wsb + OFF_KL);
    const short* __restrict__ Qhg = (const short*)(wsb + OFF_QH);
    const short* __restrict__ Qlg = (const short*)(wsb + OFF_QL);
    const short* __restrict__ Vthg = (const short*)(wsb + OFF_VTH);
    const short* __restrict__ Vtlg = (const short*)(wsb + OFF_VTL);

    const int tid = threadIdx.x;
    const int w = tid >> 6, l = tid & 63;
    const int l15 = l & 15, l4 = l >> 4;
    const int bx = blockIdx.x;
    const int jh = bx & 1, it = (bx >> 1) & 63, b = bx >> 7;
    const int i0m = b*S_ + it*64;
    const int jbase = jh*(S_/2);

    // persistent K fragments (A-frag: row = l15, k = 8*l4 + e, per 32-k step)
    bf16x8 kh0, kh1, kl0, kl1;
    {
        const size_t row = (size_t)(i0m + 16*w + l15) * 64;
        kh0 = *(const bf16x8*)(Khg + row + 8*l4);
        kh1 = *(const bf16x8*)(Khg + row + 32 + 8*l4);
        kl0 = *(const bf16x8*)(Klg + row + 8*l4);
        kl1 = *(const bf16x8*)(Klg + row + 32 + 8*l4);
    }

    // staging geometry: 2 rounds of 16B per buffer per thread
    const int jr0 = tid >> 3;            // 0..31
    const int jr1 = jr0 + 32;            // 32..63
    const int c00 = (tid & 7) * 8;       // 0..56
    const int sidx0 = jr0*64 + (c00 ^ ((jr0 & 7) << 3));
    const int sidx1 = jr1*64 + (c00 ^ ((jr1 & 7) << 3));

    u16x8 pq_h0, pq_h1, pq_l0, pq_l1, pv_h0, pv_h1, pv_l0, pv_l1;
    int mp0, mp1, mp2, mp3;

#define PRELOAD(JC) do {                                                       \
    const size_t qb = (size_t)(b*S_ + (JC));                                   \
    pq_h0 = *(const u16x8*)(Qhg + (qb + jr0)*64 + c00);                        \
    pq_h1 = *(const u16x8*)(Qhg + (qb + jr1)*64 + c00);                        \
    pq_l0 = *(const u16x8*)(Qlg + (qb + jr0)*64 + c00);                        \
    pq_l1 = *(const u16x8*)(Qlg + (qb + jr1)*64 + c00);                        \
    pv_h0 = *(const u16x8*)(Vthg + (size_t)jr0*M_ + qb + c00);                 \
    pv_h1 = *(const u16x8*)(Vthg + (size_t)jr1*M_ + qb + c00);                 \
    pv_l0 = *(const u16x8*)(Vtlg + (size_t)jr0*M_ + qb + c00);                 \
    pv_l1 = *(const u16x8*)(Vtlg + (size_t)jr1*M_ + qb + c00);                 \
    mp0 = maskp[b*S_ + (JC) + l15];                                            \
    mp1 = maskp[b*S_ + (JC) + 16 + l15];                                       \
    mp2 = maskp[b*S_ + (JC) + 32 + l15];                                       \
    mp3 = maskp[b*S_ + (JC) + 48 + l15];                                       \
} while (0)

    PRELOAD(jbase);

    f32x4 acc_o0 = {0.f,0.f,0.f,0.f}, acc_o1 = {0.f,0.f,0.f,0.f};
    f32x4 acc_o2 = {0.f,0.f,0.f,0.f}, acc_o3 = {0.f,0.f,0.f,0.f};
    float mi[4], li[4];
    #pragma unroll
    for (int e = 0; e < 4; ++e) { mi[e] = -INFINITY; li[e] = 0.f; }

    for (int jc = jbase; jc < jbase + S_/2; jc += 64) {
        __syncthreads();                       // all waves done reading prev Q/V
        *(u16x8*)(Qh + sidx0) = pq_h0;  *(u16x8*)(Qh + sidx1) = pq_h1;
        *(u16x8*)(Ql + sidx0) = pq_l0;  *(u16x8*)(Ql + sidx1) = pq_l1;
        *(u16x8*)(Vh + sidx0) = pv_h0;  *(u16x8*)(Vh + sidx1) = pv_h1;
        *(u16x8*)(Vl + sidx0) = pv_l0;  *(u16x8*)(Vl + sidx1) = pv_l1;
        const int mc0 = mp0, mc1 = mp1, mc2 = mp2, mc3 = mp3;
        int jn = jc + 64; if (jn >= jbase + S_/2) jn = jbase;
        PRELOAD(jn);                           // issue-early; hides under compute
        __syncthreads();                       // staging visible

        // ---- QK^T (split-bf16: hh + hl + lh) ----
        f32x4 s0 = {0.f,0.f,0.f,0.f}, s1 = {0.f,0.f,0.f,0.f};
        f32x4 s2 = {0.f,0.f,0.f,0.f}, s3 = {0.f,0.f,0.f,0.f};
        #pragma unroll
        for (int ks = 0; ks < 2; ++ks) {
            const bf16x8 ka = ks ? kh1 : kh0;
            const bf16x8 kb = ks ? kl1 : kl0;
            const int cofs = (32*ks + 8*l4) ^ ((l15 & 7) << 3);
            {
                const int qi = (0*16 + l15)*64 + cofs;
                bf16x8 qh = *(const bf16x8*)(Qh + qi);
                bf16x8 ql = *(const bf16x8*)(Ql + qi);
                s0 = __builtin_amdgcn_mfma_f32_16x16x32_bf16(ka, qh, s0, 0, 0, 0);
                s0 = __builtin_amdgcn_mfma_f32_16x16x32_bf16(ka, ql, s0, 0, 0, 0);
                s0 = __builtin_amdgcn_mfma_f32_16x16x32_bf16(kb, qh, s0, 0, 0, 0);
            }
            {
                const int qi = (1*16 + l15)*64 + cofs;
                bf16x8 qh = *(const bf16x8*)(Qh + qi);
                bf16x8 ql = *(const bf16x8*)(Ql + qi);
                s1 = __builtin_amdgcn_mfma_f32_16x16x32_bf16(ka, qh, s1, 0, 0, 0);
                s1 = __builtin_amdgcn_mfma_f32_16x16x32_bf16(ka, ql, s1, 0, 0, 0);
                s1 = __builtin_amdgcn_mfma_f32_16x16x32_bf16(kb, qh, s1, 0, 0, 0);
            }
            {
                const int qi = (2*16 + l15)*64 + cofs;
                bf16x8 qh = *(const bf16x8*)(Qh + qi);
                bf16x8 ql = *(const bf16x8*)(Ql + qi);
                s2 = __builtin_amdgcn_mfma_f32_16x16x32_bf16(ka, qh, s2, 0, 0, 0);
                s2 = __builtin_amdgcn_mfma_f32_16x16x32_bf16(ka, ql, s2, 0, 0, 0);
                s2 = __builtin_amdgcn_mfma_f32_16x16x32_bf16(kb, qh, s2, 0, 0, 0);
            }
            {
                const int qi = (3*16 + l15)*64 + cofs;
                bf16x8 qh = *(const bf16x8*)(Qh + qi);
                bf16x8 ql = *(const bf16x8*)(Ql + qi);
                s3 = __builtin_amdgcn_mfma_f32_16x16x32_bf16(ka, qh, s3, 0, 0, 0);
                s3 = __builtin_amdgcn_mfma_f32_16x16x32_bf16(ka, ql, s3, 0, 0, 0);
                s3 = __builtin_amdgcn_mfma_f32_16x16x32_bf16(kb, qh, s3, 0, 0, 0);
            }
        }

        // ---- online softmax (rows = 4*l4+e; reduce across 16 lanes) ----
        #pragma unroll
        for (int e = 0; e < 4; ++e) {
            float sv0 = mc0 ? s0[e]*0.125f : NEGINF;
            float sv1 = mc1 ? s1[e]*0.125f : NEGINF;
            float sv2 = mc2 ? s2[e]*0.125f : NEGINF;
            float sv3 = mc3 ? s3[e]*0.125f : NEGINF;
            float rm = fmaxf(fmaxf(sv0, sv1), fmaxf(sv2, sv3));
            rm = fmaxf(rm, __shfl_xor(rm, 1));
            rm = fmaxf(rm, __shfl_xor(rm, 2));
            rm = fmaxf(rm, __shfl_xor(rm, 4));
            rm = fmaxf(rm, __shfl_xor(rm, 8));
            const float mnew = fmaxf(mi[e], rm);
            const float alpha = __expf(mi[e] - mnew);
            const float p0 = __expf(sv0 - mnew);
            const float p1 = __expf(sv1 - mnew);
            const float p2 = __expf(sv2 - mnew);
            const float p3 = __expf(sv3 - mnew);
            float lsum = p0 + p1 + p2 + p3;
            lsum += __shfl_xor(lsum, 1);
            lsum += __shfl_xor(lsum, 2);
            lsum += __shfl_xor(lsum, 4);
            lsum += __shfl_xor(lsum, 8);
            li[e] = li[e]*alpha + lsum;
            mi[e] = mnew;
            const int il = 4*l4 + e;
            const int swz = (il & 7) << 3;
            unsigned short h0 = f2bf(p0); Ph[w][il*64 + ((     l15) ^ swz)] = (short)h0;
            unsigned short h1 = f2bf(p1); Ph[w][il*64 + ((16 + l15) ^ swz)] = (short)h1;
            unsigned short h2 = f2bf(p2); Ph[w][il*64 + ((32 + l15) ^ swz)] = (short)h2;
            unsigned short h3 = f2bf(p3); Ph[w][il*64 + ((48 + l15) ^ swz)] = (short)h3;
            Pl[w][il*64 + ((     l15) ^ swz)] = (short)f2bf(p0 - bf2f(h0));
            Pl[w][il*64 + ((16 + l15) ^ swz)] = (short)f2bf(p1 - bf2f(h1));
            Pl[w][il*64 + ((32 + l15) ^ swz)] = (short)f2bf(p2 - bf2f(h2));
            Pl[w][il*64 + ((48 + l15) ^ swz)] = (short)f2bf(p3 - bf2f(h3));
            acc_o0[e] *= alpha; acc_o1[e] *= alpha; acc_o2[e] *= alpha; acc_o3[e] *= alpha;
        }

        // ---- PV (split-bf16) ----
        #pragma unroll
        for (int ks = 0; ks < 2; ++ks) {
            const int cofs = (32*ks + 8*l4) ^ ((l15 & 7) << 3);
            const int pidx = l15*64 + cofs;
            bf16x8 pah = *(const bf16x8*)(&Ph[w][0] + pidx);
            bf16x8 pal = *(const bf16x8*)(&Pl[w][0] + pidx);
            {
                const int vi = (0*16 + l15)*64 + cofs;
                bf16x8 vh = *(const bf16x8*)(Vh + vi);
                bf16x8 vl = *(const bf16x8*)(Vl + vi);
                acc_o0 = __builtin_amdgcn_mfma_f32_16x16x32_bf16(pah, vh, acc_o0, 0, 0, 0);
                acc_o0 = __builtin_amdgcn_mfma_f32_16x16x32_bf16(pah, vl, acc_o0, 0, 0, 0);
                acc_o0 = __builtin_amdgcn_mfma_f32_16x16x32_bf16(pal, vh, acc_o0, 0, 0, 0);
            }
            {
                const int vi = (1*16 + l15)*64 + cofs;
                bf16x8 vh = *(const bf16x8*)(Vh + vi);
                bf16x8 vl = *(const bf16x8*)(Vl + vi);
                acc_o1 = __builtin_amdgcn_mfma_f32_16x16x32_bf16(pah, vh, acc_o1, 0, 0, 0);
                acc_o1 = __builtin_amdgcn_mfma_f32_16x16x32_bf16(pah, vl, acc_o1, 0, 0, 0);
                acc_o1 = __builtin_amdgcn_mfma_f32_16x16x32_bf16(pal, vh, acc_o1, 0, 0, 0);
            }
            {
                const int vi = (2*16 + l15)*64 + cofs;
                bf16x8 vh = *(const bf16x8*)(Vh + vi);
                bf16x8 vl = *(const bf16x8*)(Vl + vi);
                acc_o2 = __builtin_amdgcn_mfma_f32_16x16x32_bf16(pah, vh, acc_o2, 0, 0, 0);
                acc_o2 = __builtin_amdgcn_mfma_f32_16x16x32_bf16(pah, vl, acc_o2, 0, 0, 0);
                acc_o2 = __builtin_amdgcn_mfma_f32_16x16x32_bf16(pal, vh, acc_o2, 0, 0, 0);
            }
            {
                const int vi = (3*16 + l15)*64 + cofs;
                bf16x8 vh = *(const bf16x8*)(Vh + vi);
                bf16x8 vl = *(const bf16x8*)(Vl + vi);
                acc_o3 = __builtin_amdgcn_mfma_f32_16x16x32_bf16(pah, vh, acc_o3, 0, 0, 0);
                acc_o3 = __builtin_amdgcn_mfma_f32_16x16x32_bf16(pah, vl, acc_o3, 0, 0, 0);
                acc_o3 = __builtin_amdgcn_mfma_f32_16x16x32_bf16(pal, vh, acc_o3, 0, 0, 0);
            }
        }
    }

    // ---- write partials (unnormalized) ----
    float* pacc = (float*)(wsb + OFF_PACC) + (size_t)bx * 4096;
    float* pm   = (float*)(wsb + OFF_PM)  + bx * 64;
    float* pl2  = (float*)(wsb + OFF_PL2) + bx * 64;
    #pragma unroll
    for (int e = 0; e < 4; ++e) {
        const int rowo = (16*w + 4*l4 + e) * 64;
        pacc[rowo +  0 + l15] = acc_o0[e];
        pacc[rowo + 16 + l15] = acc_o1[e];
        pacc[rowo + 32 + l15] = acc_o2[e];
        pacc[rowo + 48 + l15] = acc_o3[e];
    }
    if (l15 == 0) {
        #pragma unroll
        for (int e = 0; e < 4; ++e) {
            pm[16*w + 4*l4 + e] = mi[e];
            pl2[16*w + 4*l4 + e] = li[e];
        }
    }
#undef PRELOAD
}

// ---------------------------------------------------------------------------
// Kernel 3: combine the two j-half partials per row and normalize.
// ---------------------------------------------------------------------------
__global__ __launch_bounds__(256)
void combine(const float* __restrict__ ws, float* __restrict__ out)
{
    const int gid = blockIdx.x * 256 + threadIdx.x;   // 0 .. 262143
    const int row = gid >> 4, q = gid & 15;
    const int b = row >> 12, it = (row >> 6) & 63, il = row & 63;
    const int pb0 = (b << 7) | (it << 1);
    const float* pacc = ws + PACC_F;
    const float* pm   = ws + PM_F;
    const float* pl   = ws + PL_F;
    const float m0 = pm[pb0*64 + il],     m1 = pm[(pb0+1)*64 + il];
    const float l0 = pl[pb0*64 + il],     l1 = pl[(pb0+1)*64 + il];
    const float M  = fmaxf(m0, m1);
    const float w0 = __expf(m0 - M), w1 = __expf(m1 - M);
    const float inv = 1.0f / (l0*w0 + l1*w1);
    const float4 a0 = *(const float4*)(pacc + (size_t)pb0*4096 + il*64 + q*4);
    const float4 a1 = *(const float4*)(pacc + (size_t)(pb0+1)*4096 + il*64 + q*4);
    float4 o;
    o.x = (a0.x*w0 + a1.x*w1) * inv;
    o.y = (a0.y*w0 + a1.y*w1) * inv;
    o.z = (a0.z*w0 + a1.z*w1) * inv;
    o.w = (a0.w*w0 + a1.w*w1) * inv;
    *(float4*)(out + (size_t)row*64 + q*4) = o;
}

// ---------------------------------------------------------------------------
extern "C" void kernel_launch(void* const* d_in, const int* in_sizes, int n_in,
                              void* d_out, int out_size, void* d_ws, size_t ws_size,
                              hipStream_t stream) {
    const float* x    = (const float*)d_in[0];
    const int*   mask = (const int*)d_in[1];
    const float* Wk   = (const float*)d_in[2];
    const float* Wq   = (const float*)d_in[3];
    const float* Wv   = (const float*)d_in[4];
    float* out = (float*)d_out;
    char*  wsb = (char*)d_ws;

    hipLaunchKernelGGL(qkv_proj,   dim3(M_/64), dim3(256), 0, stream, x, Wk, Wq, Wv, wsb);
    hipLaunchKernelGGL(flash_mfma, dim3(512),   dim3(256), 0, stream, mask, wsb);
    hipLaunchKernelGGL(combine,    dim3(1024),  dim3(256), 0, stream, (const float*)d_ws, out);
}

// Round 3
// 188.611 us; speedup vs baseline: 14.7520x; 1.6474x over previous
//
#include <hip/hip_runtime.h>
#include <hip/hip_bf16.h>
#include <math.h>

#define B_ 4
#define S_ 4096
#define H_ 1024
#define D_ 64
#define M_ (B_*S_)            // 16384 rows
#define NEGINF (-1.0e12f)

typedef __attribute__((ext_vector_type(8))) short bf16x8;
typedef __attribute__((ext_vector_type(8))) unsigned short u16x8;
typedef __attribute__((ext_vector_type(8))) _Float16 f16x8;
typedef __attribute__((ext_vector_type(4))) _Float16 f16x4;
typedef __attribute__((ext_vector_type(4))) float f32x4;

// ---- workspace byte offsets ----
#define OFF_WH   0                         // short [192][1024] bf16-hi of W rows
#define OFF_WL   393216                    // short [192][1024] bf16-lo
#define OFF_KF   786432                    // _Float16 [16384][64]
#define OFF_QF   2883584                   // _Float16 [16384][64]
#define OFF_VTF  4980736                   // _Float16 [64][16384] (V transposed)
#define OFF_PACC 7077888                   // float [1024][4096]
#define OFF_PM   23855104                  // float [1024][64]
#define OFF_PL2  24117248                  // float [1024][64]

__device__ __forceinline__ unsigned short f2bf_rne(float f) {
    union { float f; unsigned u; } v; v.f = f;
    unsigned r = (v.u + 0x7fffu + ((v.u >> 16) & 1u)) >> 16;
    return (unsigned short)r;
}
__device__ __forceinline__ float bf2f(unsigned short h) {
    union { unsigned u; float f; } v; v.u = ((unsigned)h) << 16;
    return v.f;
}
// split fp32 -> bf16 hi (truncate) + bf16 lo (RNE of remainder)
__device__ __forceinline__ void split1(float f, unsigned short& h, unsigned short& l) {
    union { float f; unsigned u; } v; v.f = f;
    h = (unsigned short)(v.u >> 16);
    l = f2bf_rne(f - bf2f(h));
}
__device__ __forceinline__ void split8(const float4& a, const float4& b, u16x8& hi, u16x8& lo) {
    float f[8] = {a.x,a.y,a.z,a.w, b.x,b.y,b.z,b.w};
    #pragma unroll
    for (int i = 0; i < 8; ++i) {
        unsigned short h, l; split1(f[i], h, l);
        hi[i] = h; lo[i] = l;
    }
}

// ---------------------------------------------------------------------------
// Kernel 0: preconvert W rows (K|Q|V stacked, 192 x 1024) to bf16 hi/lo.
// ---------------------------------------------------------------------------
__global__ __launch_bounds__(256)
void wconv(const float* __restrict__ Wk, const float* __restrict__ Wq,
           const float* __restrict__ Wv, char* __restrict__ wsb)
{
    short* Wh = (short*)(wsb + OFF_WH);
    short* Wl = (short*)(wsb + OFF_WL);
    const int n = blockIdx.x;          // 0..191
    const int t = threadIdx.x;         // 0..255
    const float* src = (n < 64) ? (Wk + (size_t)n*H_)
                     : (n < 128 ? (Wq + (size_t)(n-64)*H_) : (Wv + (size_t)(n-128)*H_));
    float4 v = *(const float4*)(src + t*4);
    unsigned short h0,l0,h1,l1,h2,l2,h3,l3;
    split1(v.x,h0,l0); split1(v.y,h1,l1); split1(v.z,h2,l2); split1(v.w,h3,l3);
    ushort4 hv; hv.x=h0; hv.y=h1; hv.z=h2; hv.w=h3;
    ushort4 lv; lv.x=l0; lv.y=l1; lv.z=l2; lv.w=l3;
    *(ushort4*)(Wh + n*1024 + t*4) = hv;
    *(ushort4*)(Wl + n*1024 + t*4) = lv;
}

// ---------------------------------------------------------------------------
// Kernel 1: QKV projection, split-bf16 MFMA (hh+hl+lh ~ fp32 accuracy).
// 256 thr = 4 waves. BM=64 (4 m-frags, all per wave), BN=192 split across
// waves (wave w owns nt = 3w..3w+2), BK=64. x staged fp32->hi/lo in LDS,
// W staged from preconverted hi/lo. Outputs fp16 K,Q and transposed V.
// ---------------------------------------------------------------------------
__global__ __launch_bounds__(256, 1)
void qkv_mfma(const float* __restrict__ x, char* __restrict__ wsb)
{
    __shared__ short Ah[4096], Al[4096];     // [64 m][64 k] swizzled
    __shared__ short Bh[12288], Bl[12288];   // [192 n][64 k] swizzled

    const short* __restrict__ Whg = (const short*)(wsb + OFF_WH);
    const short* __restrict__ Wlg = (const short*)(wsb + OFF_WL);
    _Float16* Kf  = (_Float16*)(wsb + OFF_KF);
    _Float16* Qf  = (_Float16*)(wsb + OFF_QF);
    _Float16* Vtf = (_Float16*)(wsb + OFF_VTF);

    const int tid = threadIdx.x;
    const int w = tid >> 6, l = tid & 63;
    const int l15 = l & 15, l4 = l >> 4;
    const int m0 = blockIdx.x * 64;

    // staging chunk geometry (8 shorts per chunk)
    const int arow0 = tid >> 3,        ac0 = (tid & 7) * 8;
    const int arow1 = (tid + 256) >> 3;
    const int aoff0 = arow0*64 + (ac0 ^ ((arow0 & 7) << 3));
    const int aoff1 = arow1*64 + (ac0 ^ ((arow1 & 7) << 3));

    float4 xa0, xa1, xa2, xa3;
    u16x8 wbh0, wbh1, wbh2, wbh3, wbh4, wbh5;
    u16x8 wbl0, wbl1, wbl2, wbl3, wbl4, wbl5;

#define QKV_PREFETCH(K0) do {                                                  \
    xa0 = *(const float4*)(x + (size_t)(m0 + arow0)*H_ + (K0) + ac0);          \
    xa1 = *(const float4*)(x + (size_t)(m0 + arow0)*H_ + (K0) + ac0 + 4);      \
    xa2 = *(const float4*)(x + (size_t)(m0 + arow1)*H_ + (K0) + ac0);          \
    xa3 = *(const float4*)(x + (size_t)(m0 + arow1)*H_ + (K0) + ac0 + 4);      \
    { int idx=tid;        int r=idx>>3, c8=(idx&7)*8;                          \
      wbh0 = *(const u16x8*)(Whg + r*1024 + (K0) + c8);                        \
      wbl0 = *(const u16x8*)(Wlg + r*1024 + (K0) + c8); }                      \
    { int idx=tid+256;    int r=idx>>3, c8=(idx&7)*8;                          \
      wbh1 = *(const u16x8*)(Whg + r*1024 + (K0) + c8);                        \
      wbl1 = *(const u16x8*)(Wlg + r*1024 + (K0) + c8); }                      \
    { int idx=tid+512;    int r=idx>>3, c8=(idx&7)*8;                          \
      wbh2 = *(const u16x8*)(Whg + r*1024 + (K0) + c8);                        \
      wbl2 = *(const u16x8*)(Wlg + r*1024 + (K0) + c8); }                      \
    { int idx=tid+768;    int r=idx>>3, c8=(idx&7)*8;                          \
      wbh3 = *(const u16x8*)(Whg + r*1024 + (K0) + c8);                        \
      wbl3 = *(const u16x8*)(Wlg + r*1024 + (K0) + c8); }                      \
    { int idx=tid+1024;   int r=idx>>3, c8=(idx&7)*8;                          \
      wbh4 = *(const u16x8*)(Whg + r*1024 + (K0) + c8);                        \
      wbl4 = *(const u16x8*)(Wlg + r*1024 + (K0) + c8); }                      \
    { int idx=tid+1280;   int r=idx>>3, c8=(idx&7)*8;                          \
      wbh5 = *(const u16x8*)(Whg + r*1024 + (K0) + c8);                        \
      wbl5 = *(const u16x8*)(Wlg + r*1024 + (K0) + c8); }                      \
} while (0)

    QKV_PREFETCH(0);

    f32x4 acc[4][3];
    #pragma unroll
    for (int ms = 0; ms < 4; ++ms)
        #pragma unroll
        for (int nl = 0; nl < 3; ++nl) acc[ms][nl] = (f32x4){0.f,0.f,0.f,0.f};

    for (int k0 = 0; k0 < H_; k0 += 64) {
        __syncthreads();
        {   // commit A (fp32 -> hi/lo)
            u16x8 h, lo8;
            split8(xa0, xa1, h, lo8);
            *(u16x8*)(Ah + aoff0) = h;  *(u16x8*)(Al + aoff0) = lo8;
            split8(xa2, xa3, h, lo8);
            *(u16x8*)(Ah + aoff1) = h;  *(u16x8*)(Al + aoff1) = lo8;
        }
        {   // commit B
            { int idx=tid;      int r=idx>>3, c8=(idx&7)*8; int off=r*64+(c8^((r&7)<<3));
              *(u16x8*)(Bh+off)=wbh0; *(u16x8*)(Bl+off)=wbl0; }
            { int idx=tid+256;  int r=idx>>3, c8=(idx&7)*8; int off=r*64+(c8^((r&7)<<3));
              *(u16x8*)(Bh+off)=wbh1; *(u16x8*)(Bl+off)=wbl1; }
            { int idx=tid+512;  int r=idx>>3, c8=(idx&7)*8; int off=r*64+(c8^((r&7)<<3));
              *(u16x8*)(Bh+off)=wbh2; *(u16x8*)(Bl+off)=wbl2; }
            { int idx=tid+768;  int r=idx>>3, c8=(idx&7)*8; int off=r*64+(c8^((r&7)<<3));
              *(u16x8*)(Bh+off)=wbh3; *(u16x8*)(Bl+off)=wbl3; }
            { int idx=tid+1024; int r=idx>>3, c8=(idx&7)*8; int off=r*64+(c8^((r&7)<<3));
              *(u16x8*)(Bh+off)=wbh4; *(u16x8*)(Bl+off)=wbl4; }
            { int idx=tid+1280; int r=idx>>3, c8=(idx&7)*8; int off=r*64+(c8^((r&7)<<3));
              *(u16x8*)(Bh+off)=wbh5; *(u16x8*)(Bl+off)=wbl5; }
        }
        int kn = (k0 + 64 < H_) ? k0 + 64 : 0;
        QKV_PREFETCH(kn);
        __syncthreads();

        #pragma unroll
        for (int ks = 0; ks < 2; ++ks) {
            const int cofs = (32*ks + 8*l4) ^ ((l15 & 7) << 3);
            bf16x8 ah[4], al[4];
            #pragma unroll
            for (int ms = 0; ms < 4; ++ms) {
                ah[ms] = *(const bf16x8*)(Ah + (16*ms + l15)*64 + cofs);
                al[ms] = *(const bf16x8*)(Al + (16*ms + l15)*64 + cofs);
            }
            #pragma unroll
            for (int nl = 0; nl < 3; ++nl) {
                const int nrow = (3*w + nl)*16 + l15;
                const int boff = nrow*64 + ((32*ks + 8*l4) ^ ((nrow & 7) << 3));
                bf16x8 bh = *(const bf16x8*)(Bh + boff);
                bf16x8 bl = *(const bf16x8*)(Bl + boff);
                #pragma unroll
                for (int ms = 0; ms < 4; ++ms) {
                    acc[ms][nl] = __builtin_amdgcn_mfma_f32_16x16x32_bf16(ah[ms], bh, acc[ms][nl], 0,0,0);
                    acc[ms][nl] = __builtin_amdgcn_mfma_f32_16x16x32_bf16(ah[ms], bl, acc[ms][nl], 0,0,0);
                    acc[ms][nl] = __builtin_amdgcn_mfma_f32_16x16x32_bf16(al[ms], bh, acc[ms][nl], 0,0,0);
                }
            }
        }
    }

    // epilogue: fp16 outputs; D[m][n]: m = m0+16ms+4*l4+e, n = nt*16+l15
    #pragma unroll
    for (int nl = 0; nl < 3; ++nl) {
        const int nt = 3*w + nl;
        const int n = nt*16 + l15;
        #pragma unroll
        for (int ms = 0; ms < 4; ++ms) {
            if (nt < 4) {
                #pragma unroll
                for (int e = 0; e < 4; ++e)
                    Kf[(size_t)(m0 + 16*ms + 4*l4 + e)*64 + n] = (_Float16)acc[ms][nl][e];
            } else if (nt < 8) {
                #pragma unroll
                for (int e = 0; e < 4; ++e)
                    Qf[(size_t)(m0 + 16*ms + 4*l4 + e)*64 + (n - 64)] = (_Float16)acc[ms][nl][e];
            } else {
                f16x4 pk;
                pk[0] = (_Float16)acc[ms][nl][0]; pk[1] = (_Float16)acc[ms][nl][1];
                pk[2] = (_Float16)acc[ms][nl][2]; pk[3] = (_Float16)acc[ms][nl][3];
                *(f16x4*)(Vtf + (size_t)(n - 128)*M_ + m0 + 16*ms + 4*l4) = pk;
            }
        }
    }
#undef QKV_PREFETCH
}

// ---------------------------------------------------------------------------
// Kernel 2: flash attention, pure fp16 MFMA. 64 i-rows/block, 4 waves
// (16 rows each), 64-j chunks, j-split x4 (grid 1024 -> 4 blocks/CU).
// LDS 24KB: Q [j][d], Vt [d][j], P per-wave [16][64], all XOR-swizzled.
// ---------------------------------------------------------------------------
__global__ __launch_bounds__(256, 4)
void flash_f16(const int* __restrict__ maskp, char* __restrict__ wsb)
{
    __shared__ _Float16 Qs[4096];       // [j][d] swizzled
    __shared__ _Float16 Vts[4096];      // [d][j] swizzled
    __shared__ _Float16 Ps[4][1024];    // per-wave [16 i][64 j] swizzled

    const _Float16* __restrict__ Kf  = (const _Float16*)(wsb + OFF_KF);
    const _Float16* __restrict__ Qf  = (const _Float16*)(wsb + OFF_QF);
    const _Float16* __restrict__ Vtf = (const _Float16*)(wsb + OFF_VTF);

    const int tid = threadIdx.x;
    const int w = tid >> 6, l = tid & 63;
    const int l15 = l & 15, l4 = l >> 4;
    const int bx = blockIdx.x;
    const int jh = bx & 3, it = (bx >> 2) & 63, b = bx >> 8;
    const int bS = b * S_;
    const int i0m = bS + it*64;
    const int jbase = jh * 1024;

    // persistent K fragments
    f16x8 kf0, kf1;
    {
        const size_t row = (size_t)(i0m + 16*w + l15) * 64;
        kf0 = *(const f16x8*)(Kf + row + 8*l4);
        kf1 = *(const f16x8*)(Kf + row + 32 + 8*l4);
    }

    const int jr0 = tid >> 3, jr1 = jr0 + 32;
    const int c0 = (tid & 7) * 8;
    const int sidx0 = jr0*64 + (c0 ^ ((jr0 & 7) << 3));
    const int sidx1 = jr1*64 + (c0 ^ ((jr1 & 7) << 3));

    u16x8 pq0, pq1, pv0, pv1;
    int mp0, mp1, mp2, mp3;

#define FL_PRELOAD(JC) do {                                                    \
    pq0 = *(const u16x8*)(Qf + (size_t)(bS + (JC) + jr0)*64 + c0);             \
    pq1 = *(const u16x8*)(Qf + (size_t)(bS + (JC) + jr1)*64 + c0);             \
    pv0 = *(const u16x8*)(Vtf + (size_t)jr0*M_ + bS + (JC) + c0);              \
    pv1 = *(const u16x8*)(Vtf + (size_t)jr1*M_ + bS + (JC) + c0);              \
    mp0 = maskp[bS + (JC) +      l15];                                         \
    mp1 = maskp[bS + (JC) + 16 + l15];                                         \
    mp2 = maskp[bS + (JC) + 32 + l15];                                         \
    mp3 = maskp[bS + (JC) + 48 + l15];                                         \
} while (0)

    FL_PRELOAD(jbase);

    f32x4 acc_o0 = {0.f,0.f,0.f,0.f}, acc_o1 = {0.f,0.f,0.f,0.f};
    f32x4 acc_o2 = {0.f,0.f,0.f,0.f}, acc_o3 = {0.f,0.f,0.f,0.f};
    float mi[4], li[4];
    #pragma unroll
    for (int e = 0; e < 4; ++e) { mi[e] = -INFINITY; li[e] = 0.f; }

    for (int jc = jbase; jc < jbase + 1024; jc += 64) {
        __syncthreads();                       // prior PV done reading LDS
        *(u16x8*)(void*)(Qs + sidx0)  = pq0;  *(u16x8*)(void*)(Qs + sidx1)  = pq1;
        *(u16x8*)(void*)(Vts + sidx0) = pv0;  *(u16x8*)(void*)(Vts + sidx1) = pv1;
        const int mc0 = mp0, mc1 = mp1, mc2 = mp2, mc3 = mp3;
        int jn = jc + 64; if (jn >= jbase + 1024) jn = jbase;
        FL_PRELOAD(jn);                        // issue-early; hides under compute
        __syncthreads();                       // staging visible

        // ---- QK^T ----
        f32x4 s0 = {0.f,0.f,0.f,0.f}, s1 = {0.f,0.f,0.f,0.f};
        f32x4 s2 = {0.f,0.f,0.f,0.f}, s3 = {0.f,0.f,0.f,0.f};
        __builtin_amdgcn_s_setprio(1);
        #pragma unroll
        for (int ks = 0; ks < 2; ++ks) {
            const f16x8 ka = ks ? kf1 : kf0;
            const int cofs = (32*ks + 8*l4) ^ ((l15 & 7) << 3);
            s0 = __builtin_amdgcn_mfma_f32_16x16x32_f16(ka, *(const f16x8*)(Qs + (0*16 + l15)*64 + cofs), s0, 0,0,0);
            s1 = __builtin_amdgcn_mfma_f32_16x16x32_f16(ka, *(const f16x8*)(Qs + (1*16 + l15)*64 + cofs), s1, 0,0,0);
            s2 = __builtin_amdgcn_mfma_f32_16x16x32_f16(ka, *(const f16x8*)(Qs + (2*16 + l15)*64 + cofs), s2, 0,0,0);
            s3 = __builtin_amdgcn_mfma_f32_16x16x32_f16(ka, *(const f16x8*)(Qs + (3*16 + l15)*64 + cofs), s3, 0,0,0);
        }
        __builtin_amdgcn_s_setprio(0);

        // ---- online softmax (rows i = 16w+4*l4+e; reduce over 16 l15 lanes) ----
        _Float16* pw = &Ps[w][0];
        #pragma unroll
        for (int e = 0; e < 4; ++e) {
            float sv0 = mc0 ? s0[e]*0.125f : NEGINF;
            float sv1 = mc1 ? s1[e]*0.125f : NEGINF;
            float sv2 = mc2 ? s2[e]*0.125f : NEGINF;
            float sv3 = mc3 ? s3[e]*0.125f : NEGINF;
            float rm = fmaxf(fmaxf(sv0, sv1), fmaxf(sv2, sv3));
            rm = fmaxf(rm, __shfl_xor(rm, 1));
            rm = fmaxf(rm, __shfl_xor(rm, 2));
            rm = fmaxf(rm, __shfl_xor(rm, 4));
            rm = fmaxf(rm, __shfl_xor(rm, 8));
            if (__ballot(rm > mi[e])) {        // defer-max: skip rescale if no growth
                const float mnew = fmaxf(mi[e], rm);
                const float alpha = __expf(mi[e] - mnew);
                li[e] *= alpha;
                acc_o0[e] *= alpha; acc_o1[e] *= alpha;
                acc_o2[e] *= alpha; acc_o3[e] *= alpha;
                mi[e] = mnew;
            }
            const float p0 = __expf(sv0 - mi[e]);
            const float p1 = __expf(sv1 - mi[e]);
            const float p2 = __expf(sv2 - mi[e]);
            const float p3 = __expf(sv3 - mi[e]);
            float lsum = p0 + p1 + p2 + p3;
            lsum += __shfl_xor(lsum, 1);
            lsum += __shfl_xor(lsum, 2);
            lsum += __shfl_xor(lsum, 4);
            lsum += __shfl_xor(lsum, 8);
            li[e] += lsum;
            const int il = 4*l4 + e;
            const int swz = (il & 7) << 3;
            pw[il*64 + ((     l15) ^ swz)] = (_Float16)p0;
            pw[il*64 + ((16 + l15) ^ swz)] = (_Float16)p1;
            pw[il*64 + ((32 + l15) ^ swz)] = (_Float16)p2;
            pw[il*64 + ((48 + l15) ^ swz)] = (_Float16)p3;
        }

        // ---- PV ---- (per-wave-private P: in-wave LDS ordering suffices)
        __builtin_amdgcn_s_setprio(1);
        #pragma unroll
        for (int ks = 0; ks < 2; ++ks) {
            const int cofs = (32*ks + 8*l4) ^ ((l15 & 7) << 3);
            f16x8 pa = *(const f16x8*)(pw + l15*64 + cofs);
            acc_o0 = __builtin_amdgcn_mfma_f32_16x16x32_f16(pa, *(const f16x8*)(Vts + (0*16 + l15)*64 + cofs), acc_o0, 0,0,0);
            acc_o1 = __builtin_amdgcn_mfma_f32_16x16x32_f16(pa, *(const f16x8*)(Vts + (1*16 + l15)*64 + cofs), acc_o1, 0,0,0);
            acc_o2 = __builtin_amdgcn_mfma_f32_16x16x32_f16(pa, *(const f16x8*)(Vts + (2*16 + l15)*64 + cofs), acc_o2, 0,0,0);
            acc_o3 = __builtin_amdgcn_mfma_f32_16x16x32_f16(pa, *(const f16x8*)(Vts + (3*16 + l15)*64 + cofs), acc_o3, 0,0,0);
        }
        __builtin_amdgcn_s_setprio(0);
    }

    // ---- write partials (unnormalized) ----
    float* pacc = (float*)(wsb + OFF_PACC) + (size_t)bx * 4096;
    float* pm   = (float*)(wsb + OFF_PM)  + bx * 64;
    float* pl2  = (float*)(wsb + OFF_PL2) + bx * 64;
    #pragma unroll
    for (int e = 0; e < 4; ++e) {
        const int rowo = (16*w + 4*l4 + e) * 64;
        pacc[rowo +  0 + l15] = acc_o0[e];
        pacc[rowo + 16 + l15] = acc_o1[e];
        pacc[rowo + 32 + l15] = acc_o2[e];
        pacc[rowo + 48 + l15] = acc_o3[e];
    }
    if (l15 == 0) {
        #pragma unroll
        for (int e = 0; e < 4; ++e) {
            pm[16*w + 4*l4 + e]  = mi[e];
            pl2[16*w + 4*l4 + e] = li[e];
        }
    }
#undef FL_PRELOAD
}

// ---------------------------------------------------------------------------
// Kernel 3: combine the four j-quarter partials per row and normalize.
// ---------------------------------------------------------------------------
__global__ __launch_bounds__(256)
void combine(const char* __restrict__ wsb, float* __restrict__ out)
{
    const float* pacc = (const float*)(wsb + OFF_PACC);
    const float* pm   = (const float*)(wsb + OFF_PM);
    const float* pl   = (const float*)(wsb + OFF_PL2);
    const int gid = blockIdx.x * 256 + threadIdx.x;   // 0 .. 262143
    const int row = gid >> 4, q = gid & 15;
    const int b = row >> 12, it = (row >> 6) & 63, il = row & 63;
    const int pb0 = b*256 + it*4;
    float m0 = pm[(pb0+0)*64 + il], m1 = pm[(pb0+1)*64 + il];
    float m2 = pm[(pb0+2)*64 + il], m3 = pm[(pb0+3)*64 + il];
    float l0 = pl[(pb0+0)*64 + il], l1 = pl[(pb0+1)*64 + il];
    float l2 = pl[(pb0+2)*64 + il], l3 = pl[(pb0+3)*64 + il];
    const float M = fmaxf(fmaxf(m0, m1), fmaxf(m2, m3));
    const float w0 = __expf(m0 - M), w1 = __expf(m1 - M);
    const float w2 = __expf(m2 - M), w3 = __expf(m3 - M);
    const float inv = 1.0f / (l0*w0 + l1*w1 + l2*w2 + l3*w3);
    const float4 a0 = *(const float4*)(pacc + (size_t)(pb0+0)*4096 + il*64 + q*4);
    const float4 a1 = *(const float4*)(pacc + (size_t)(pb0+1)*4096 + il*64 + q*4);
    const float4 a2 = *(const float4*)(pacc + (size_t)(pb0+2)*4096 + il*64 + q*4);
    const float4 a3 = *(const float4*)(pacc + (size_t)(pb0+3)*4096 + il*64 + q*4);
    float4 o;
    o.x = (a0.x*w0 + a1.x*w1 + a2.x*w2 + a3.x*w3) * inv;
    o.y = (a0.y*w0 + a1.y*w1 + a2.y*w2 + a3.y*w3) * inv;
    o.z = (a0.z*w0 + a1.z*w1 + a2.z*w2 + a3.z*w3) * inv;
    o.w = (a0.w*w0 + a1.w*w1 + a2.w*w2 + a3.w*w3) * inv;
    *(float4*)(out + (size_t)row*64 + q*4) = o;
}

// ---------------------------------------------------------------------------
extern "C" void kernel_launch(void* const* d_in, const int* in_sizes, int n_in,
                              void* d_out, int out_size, void* d_ws, size_t ws_size,
                              hipStream_t stream) {
    const float* x    = (const float*)d_in[0];
    const int*   mask = (const int*)d_in[1];
    const float* Wk   = (const float*)d_in[2];
    const float* Wq   = (const float*)d_in[3];
    const float* Wv   = (const float*)d_in[4];
    float* out = (float*)d_out;
    char*  wsb = (char*)d_ws;

    hipLaunchKernelGGL(wconv,     dim3(192),  dim3(256), 0, stream, Wk, Wq, Wv, wsb);
    hipLaunchKernelGGL(qkv_mfma,  dim3(M_/64),dim3(256), 0, stream, x, wsb);
    hipLaunchKernelGGL(flash_f16, dim3(1024), dim3(256), 0, stream, mask, wsb);
    hipLaunchKernelGGL(combine,   dim3(1024), dim3(256), 0, stream, wsb, out);
}

// Round 6
// 168.567 us; speedup vs baseline: 16.5062x; 1.1189x over previous
//
#include <hip/hip_runtime.h>
#include <hip/hip_bf16.h>
#include <math.h>

#define B_ 4
#define S_ 4096
#define H_ 1024
#define D_ 64
#define M_ (B_*S_)            // 16384 rows
#define NEGINF (-1.0e12f)
#define LOG2E 1.4426950408889634f

typedef __attribute__((ext_vector_type(8))) short bf16x8;
typedef __attribute__((ext_vector_type(8))) unsigned short u16x8;
typedef __attribute__((ext_vector_type(8))) _Float16 f16x8;
typedef __attribute__((ext_vector_type(4))) _Float16 f16x4;
typedef __attribute__((ext_vector_type(4))) float f32x4;

// ---- workspace byte offsets ----
#define OFF_WH   0                         // short [192][1024] bf16-hi of W rows
#define OFF_WL   393216                    // short [192][1024] bf16-lo
#define OFF_KF   786432                    // _Float16 [16384][64]
#define OFF_QF   2883584                   // _Float16 [16384][64]
#define OFF_VTF  4980736                   // _Float16 [64][16384] (V transposed)
#define OFF_PACC 7077888                   // float [512 blocks][128 rows][64]
#define OFF_PM   23855104                  // float [512][128]  (log2-domain max)
#define OFF_PL2  24117248                  // float [512][128]

__device__ __forceinline__ unsigned short f2bf_rne(float f) {
    union { float f; unsigned u; } v; v.f = f;
    unsigned r = (v.u + 0x7fffu + ((v.u >> 16) & 1u)) >> 16;
    return (unsigned short)r;
}
__device__ __forceinline__ float bf2f(unsigned short h) {
    union { unsigned u; float f; } v; v.u = ((unsigned)h) << 16;
    return v.f;
}
// split fp32 -> bf16 hi (truncate) + bf16 lo (RNE of remainder)
__device__ __forceinline__ void split1(float f, unsigned short& h, unsigned short& l) {
    union { float f; unsigned u; } v; v.f = f;
    h = (unsigned short)(v.u >> 16);
    l = f2bf_rne(f - bf2f(h));
}

// ---------------------------------------------------------------------------
// Kernel 0: preconvert W rows (K|Q|V stacked, 192 x 1024) to bf16 hi/lo.
// ---------------------------------------------------------------------------
__global__ __launch_bounds__(256)
void wconv(const float* __restrict__ Wk, const float* __restrict__ Wq,
           const float* __restrict__ Wv, char* __restrict__ wsb)
{
    short* Wh = (short*)(wsb + OFF_WH);
    short* Wl = (short*)(wsb + OFF_WL);
    const int n = blockIdx.x;          // 0..191
    const int t = threadIdx.x;         // 0..255
    const float* src = (n < 64) ? (Wk + (size_t)n*H_)
                     : (n < 128 ? (Wq + (size_t)(n-64)*H_) : (Wv + (size_t)(n-128)*H_));
    float4 v = *(const float4*)(src + t*4);
    unsigned short h0,l0,h1,l1,h2,l2,h3,l3;
    split1(v.x,h0,l0); split1(v.y,h1,l1); split1(v.z,h2,l2); split1(v.w,h3,l3);
    ushort4 hv; hv.x=h0; hv.y=h1; hv.z=h2; hv.w=h3;
    ushort4 lv; lv.x=l0; lv.y=l1; lv.z=l2; lv.w=l3;
    *(ushort4*)(Wh + n*1024 + t*4) = hv;
    *(ushort4*)(Wl + n*1024 + t*4) = lv;
}

// ---------------------------------------------------------------------------
// Kernel 1: QKV projection, split-bf16 MFMA (hh+hl+lh ~ fp32 accuracy).
// 512 thr = 8 waves (2m x 4n). BM=32, BN=192, BK=64. grid=512 -> 2 blocks/CU,
// 4 waves/SIMD (was 1/SIMD in R3 -> latency-bound). Outputs fp16 K,Q,V^T.
// ---------------------------------------------------------------------------
__global__ __launch_bounds__(512, 4)
void qkv_mfma(const float* __restrict__ x, char* __restrict__ wsb)
{
    __shared__ __align__(16) short Ah[2048], Al[2048];     // [32 m][64 k] swz
    __shared__ __align__(16) short Bh[12288], Bl[12288];   // [192 n][64 k] swz

    const short* __restrict__ Whg = (const short*)(wsb + OFF_WH);
    const short* __restrict__ Wlg = (const short*)(wsb + OFF_WL);
    _Float16* Kf  = (_Float16*)(wsb + OFF_KF);
    _Float16* Qf  = (_Float16*)(wsb + OFF_QF);
    _Float16* Vtf = (_Float16*)(wsb + OFF_VTF);

    const int tid = threadIdx.x;
    const int w = tid >> 6, l = tid & 63;
    const int l15 = l & 15, l4 = l >> 4;
    const int wm = w & 1, wn = w >> 1;
    const int m0 = blockIdx.x * 32;

    // A staging: one float4 per thread (32x64 fp32)
    const int arow = tid >> 4, ac0 = (tid & 15) * 4;
    const int aoff = arow*64 + (ac0 ^ ((arow & 7) << 3));

    float4 xa;
    u16x8 wbh0, wbh1, wbh2, wbl0, wbl1, wbl2;

#define QKV_PREFETCH(K0) do {                                                  \
    xa = *(const float4*)(x + (size_t)(m0 + arow)*H_ + (K0) + ac0);            \
    { int idx = tid;        int r = idx >> 3, c8 = (idx & 7)*8;                \
      wbh0 = *(const u16x8*)(Whg + r*1024 + (K0) + c8);                        \
      wbl0 = *(const u16x8*)(Wlg + r*1024 + (K0) + c8); }                      \
    { int idx = tid + 512;  int r = idx >> 3, c8 = (idx & 7)*8;                \
      wbh1 = *(const u16x8*)(Whg + r*1024 + (K0) + c8);                        \
      wbl1 = *(const u16x8*)(Wlg + r*1024 + (K0) + c8); }                      \
    { int idx = tid + 1024; int r = idx >> 3, c8 = (idx & 7)*8;                \
      wbh2 = *(const u16x8*)(Whg + r*1024 + (K0) + c8);                        \
      wbl2 = *(const u16x8*)(Wlg + r*1024 + (K0) + c8); }                      \
} while (0)

    QKV_PREFETCH(0);

    f32x4 acc0 = {0.f,0.f,0.f,0.f}, acc1 = {0.f,0.f,0.f,0.f}, acc2 = {0.f,0.f,0.f,0.f};

    for (int k0 = 0; k0 < H_; k0 += 64) {
        __syncthreads();
        {   // commit A (fp32 -> hi/lo)
            unsigned short h0,l0,h1,l1,h2,l2,h3,l3;
            split1(xa.x,h0,l0); split1(xa.y,h1,l1);
            split1(xa.z,h2,l2); split1(xa.w,h3,l3);
            ushort4 hv; hv.x=h0; hv.y=h1; hv.z=h2; hv.w=h3;
            ushort4 lv; lv.x=l0; lv.y=l1; lv.z=l2; lv.w=l3;
            *(ushort4*)(Ah + aoff) = hv;
            *(ushort4*)(Al + aoff) = lv;
        }
        {   // commit B
            { int idx = tid;        int r = idx>>3, c8 = (idx&7)*8; int off = r*64 + (c8 ^ ((r&7)<<3));
              *(u16x8*)(Bh + off) = wbh0; *(u16x8*)(Bl + off) = wbl0; }
            { int idx = tid + 512;  int r = idx>>3, c8 = (idx&7)*8; int off = r*64 + (c8 ^ ((r&7)<<3));
              *(u16x8*)(Bh + off) = wbh1; *(u16x8*)(Bl + off) = wbl1; }
            { int idx = tid + 1024; int r = idx>>3, c8 = (idx&7)*8; int off = r*64 + (c8 ^ ((r&7)<<3));
              *(u16x8*)(Bh + off) = wbh2; *(u16x8*)(Bl + off) = wbl2; }
        }
        int kn = (k0 + 64 < H_) ? k0 + 64 : 0;
        QKV_PREFETCH(kn);
        __syncthreads();

        __builtin_amdgcn_s_setprio(1);
        #pragma unroll
        for (int ks = 0; ks < 2; ++ks) {
            const int cofs = (32*ks + 8*l4) ^ ((l15 & 7) << 3);
            const bf16x8 ah = *(const bf16x8*)(Ah + (16*wm + l15)*64 + cofs);
            const bf16x8 al8 = *(const bf16x8*)(Al + (16*wm + l15)*64 + cofs);
            #pragma unroll
            for (int nl = 0; nl < 3; ++nl) {
                const int nrow = (3*wn + nl)*16 + l15;
                const int boff = nrow*64 + ((32*ks + 8*l4) ^ ((nrow & 7) << 3));
                const bf16x8 bh = *(const bf16x8*)(Bh + boff);
                const bf16x8 bl8 = *(const bf16x8*)(Bl + boff);
                f32x4* ac = (nl == 0) ? &acc0 : ((nl == 1) ? &acc1 : &acc2);
                *ac = __builtin_amdgcn_mfma_f32_16x16x32_bf16(ah, bh, *ac, 0,0,0);
                *ac = __builtin_amdgcn_mfma_f32_16x16x32_bf16(ah, bl8, *ac, 0,0,0);
                *ac = __builtin_amdgcn_mfma_f32_16x16x32_bf16(al8, bh, *ac, 0,0,0);
            }
        }
        __builtin_amdgcn_s_setprio(0);
    }

    // epilogue: fp16 outputs; D[m][n]: m = m0+16wm+4*l4+e, n = nt*16+l15
    #pragma unroll
    for (int nl = 0; nl < 3; ++nl) {
        const int nt = 3*wn + nl;
        const int n = nt*16 + l15;
        const f32x4 av = (nl == 0) ? acc0 : ((nl == 1) ? acc1 : acc2);
        if (nt < 4) {
            #pragma unroll
            for (int e = 0; e < 4; ++e)
                Kf[(size_t)(m0 + 16*wm + 4*l4 + e)*64 + n] = (_Float16)av[e];
        } else if (nt < 8) {
            #pragma unroll
            for (int e = 0; e < 4; ++e)
                Qf[(size_t)(m0 + 16*wm + 4*l4 + e)*64 + (n - 64)] = (_Float16)av[e];
        } else {
            f16x4 pk;
            pk[0] = (_Float16)av[0]; pk[1] = (_Float16)av[1];
            pk[2] = (_Float16)av[2]; pk[3] = (_Float16)av[3];
            *(f16x4*)(Vtf + (size_t)(n - 128)*M_ + m0 + 16*wm + 4*l4) = pk;
        }
    }
#undef QKV_PREFETCH
}

// ---------------------------------------------------------------------------
// Kernel 2: flash attention, fp16 MFMA, SWAPPED QK^T (A=Q, B=K) so each lane
// owns one full softmax row (i=l15, 16 j-values in regs). 8 waves/block,
// i-tile 128, KVBLK=64, j-split x4 (grid 512 -> 2 blocks/CU). exp2 domain.
// LDS 32KB: Qs [j][d], Vts [d][j], Ps per-wave [16 i][64 j], all XOR-swizzled.
// ---------------------------------------------------------------------------
__global__ __launch_bounds__(512, 4)
void flash_f16(const int* __restrict__ maskp, char* __restrict__ wsb)
{
    __shared__ __align__(16) _Float16 Qs[4096];      // [64 j][64 d] swz
    __shared__ __align__(16) _Float16 Vts[4096];     // [64 d][64 j] swz
    __shared__ __align__(16) _Float16 Ps[8][1024];   // per-wave [16 i][64 j] swz

    const _Float16* __restrict__ Kf  = (const _Float16*)(wsb + OFF_KF);
    const _Float16* __restrict__ Qf  = (const _Float16*)(wsb + OFF_QF);
    const _Float16* __restrict__ Vtf = (const _Float16*)(wsb + OFF_VTF);

    const int tid = threadIdx.x;
    const int w = tid >> 6, l = tid & 63;
    const int l15 = l & 15, l4 = l >> 4;
    const int bx = blockIdx.x;
    const int jh = bx & 3, it = (bx >> 2) & 31, b = bx >> 7;
    const int bS = b * S_;
    const int i0m = bS + it*128;
    const int jbase = jh * 1024;
    const float SC = 0.125f * LOG2E;     // scale folded with log2(e)

    // persistent K fragments (B-operand: lane holds K[i=l15][k=8*l4+e])
    f16x8 kf0, kf1;
    {
        const size_t row = (size_t)(i0m + 16*w + l15) * 64;
        kf0 = *(const f16x8*)(Kf + row + 8*l4);
        kf1 = *(const f16x8*)(Kf + row + 32 + 8*l4);
    }

    const int jr = tid >> 3;             // 0..63
    const int c0 = (tid & 7) * 8;
    const int sidx = jr*64 + (c0 ^ ((jr & 7) << 3));

    u16x8 pq, pv;
    int4 mm0, mm1, mm2, mm3;

#define PRELOAD_QV(JC) do {                                                    \
    pq = *(const u16x8*)(Qf + (size_t)(bS + (JC) + jr)*64 + c0);               \
    pv = *(const u16x8*)(Vtf + (size_t)jr*M_ + bS + (JC) + c0);                \
} while (0)
#define PRELOAD_MK(JC) do {                                                    \
    mm0 = *(const int4*)(maskp + bS + (JC) +  0 + 4*l4);                       \
    mm1 = *(const int4*)(maskp + bS + (JC) + 16 + 4*l4);                       \
    mm2 = *(const int4*)(maskp + bS + (JC) + 32 + 4*l4);                       \
    mm3 = *(const int4*)(maskp + bS + (JC) + 48 + 4*l4);                       \
} while (0)

    PRELOAD_QV(jbase);
    PRELOAD_MK(jbase);

    f32x4 acc0 = {0.f,0.f,0.f,0.f}, acc1 = {0.f,0.f,0.f,0.f};
    f32x4 acc2 = {0.f,0.f,0.f,0.f}, acc3 = {0.f,0.f,0.f,0.f};
    float mi = -INFINITY, li = 0.f;      // state for row i = l15 (dup over l4)

    for (int jc = jbase; jc < jbase + 1024; jc += 64) {
        __syncthreads();                       // prior chunk done reading LDS
        *(u16x8*)(void*)(Qs + sidx)  = pq;
        *(u16x8*)(void*)(Vts + sidx) = pv;
        __syncthreads();                       // staging visible
        int jn = jc + 64; if (jn >= jbase + 1024) jn = jbase;
        PRELOAD_QV(jn);                        // hides under compute

        // ---- QK^T swapped: D[j-row][i-col]; lane -> 16 j for i=l15 ----
        f32x4 sq0 = {0.f,0.f,0.f,0.f}, sq1 = {0.f,0.f,0.f,0.f};
        f32x4 sq2 = {0.f,0.f,0.f,0.f}, sq3 = {0.f,0.f,0.f,0.f};
        __builtin_amdgcn_s_setprio(1);
        #pragma unroll
        for (int ks = 0; ks < 2; ++ks) {
            const f16x8 ka = ks ? kf1 : kf0;
            const int cofs = (32*ks + 8*l4) ^ ((l15 & 7) << 3);
            sq0 = __builtin_amdgcn_mfma_f32_16x16x32_f16(*(const f16x8*)(Qs + (0*16 + l15)*64 + cofs), ka, sq0, 0,0,0);
            sq1 = __builtin_amdgcn_mfma_f32_16x16x32_f16(*(const f16x8*)(Qs + (1*16 + l15)*64 + cofs), ka, sq1, 0,0,0);
            sq2 = __builtin_amdgcn_mfma_f32_16x16x32_f16(*(const f16x8*)(Qs + (2*16 + l15)*64 + cofs), ka, sq2, 0,0,0);
            sq3 = __builtin_amdgcn_mfma_f32_16x16x32_f16(*(const f16x8*)(Qs + (3*16 + l15)*64 + cofs), ka, sq3, 0,0,0);
        }
        __builtin_amdgcn_s_setprio(0);

        // ---- softmax: 16 in-register values, reduce over l4 via 2 shfl ----
        float sv[16];
        sv[ 0] = mm0.x ? sq0[0]*SC : NEGINF;  sv[ 1] = mm0.y ? sq0[1]*SC : NEGINF;
        sv[ 2] = mm0.z ? sq0[2]*SC : NEGINF;  sv[ 3] = mm0.w ? sq0[3]*SC : NEGINF;
        sv[ 4] = mm1.x ? sq1[0]*SC : NEGINF;  sv[ 5] = mm1.y ? sq1[1]*SC : NEGINF;
        sv[ 6] = mm1.z ? sq1[2]*SC : NEGINF;  sv[ 7] = mm1.w ? sq1[3]*SC : NEGINF;
        sv[ 8] = mm2.x ? sq2[0]*SC : NEGINF;  sv[ 9] = mm2.y ? sq2[1]*SC : NEGINF;
        sv[10] = mm2.z ? sq2[2]*SC : NEGINF;  sv[11] = mm2.w ? sq2[3]*SC : NEGINF;
        sv[12] = mm3.x ? sq3[0]*SC : NEGINF;  sv[13] = mm3.y ? sq3[1]*SC : NEGINF;
        sv[14] = mm3.z ? sq3[2]*SC : NEGINF;  sv[15] = mm3.w ? sq3[3]*SC : NEGINF;

        float rm = sv[0];
        #pragma unroll
        for (int k = 1; k < 16; ++k) rm = fmaxf(rm, sv[k]);
        rm = fmaxf(rm, __shfl_xor(rm, 16));
        rm = fmaxf(rm, __shfl_xor(rm, 32));

        if (__ballot(rm > mi + 8.0f)) {        // defer-max (log2 units)
            const float mnew = fmaxf(mi, rm);
            const float alpha = exp2f(mi - mnew);
            li *= alpha; mi = mnew;
            // acc row e is i=4*l4+e; alpha for it lives in lane l15=4*l4+e
            const float a0 = __shfl(alpha, 4*l4 + 0);
            const float a1 = __shfl(alpha, 4*l4 + 1);
            const float a2 = __shfl(alpha, 4*l4 + 2);
            const float a3 = __shfl(alpha, 4*l4 + 3);
            acc0[0]*=a0; acc0[1]*=a1; acc0[2]*=a2; acc0[3]*=a3;
            acc1[0]*=a0; acc1[1]*=a1; acc1[2]*=a2; acc1[3]*=a3;
            acc2[0]*=a0; acc2[1]*=a1; acc2[2]*=a2; acc2[3]*=a3;
            acc3[0]*=a0; acc3[1]*=a1; acc3[2]*=a2; acc3[3]*=a3;
        }

        float p[16];
        float sum = 0.f;
        #pragma unroll
        for (int k = 0; k < 16; ++k) { p[k] = exp2f(sv[k] - mi); sum += p[k]; }
        sum += __shfl_xor(sum, 16);
        sum += __shfl_xor(sum, 32);
        li += sum;

        // ---- stage P (row-major [i=l15][j], b64 packs, wave-private) ----
        _Float16* pw = &Ps[w][0];
        #pragma unroll
        for (int mf = 0; mf < 4; ++mf) {
            f16x4 pk;
            pk[0] = (_Float16)p[4*mf+0]; pk[1] = (_Float16)p[4*mf+1];
            pk[2] = (_Float16)p[4*mf+2]; pk[3] = (_Float16)p[4*mf+3];
            *(f16x4*)(pw + l15*64 + ((16*mf + 4*l4) ^ ((l15 & 7) << 3))) = pk;
        }
        PRELOAD_MK(jn);                        // masks for next chunk (L2 hit)

        // ---- PV: out[i][d] += P[i][j] V[j][d] ----
        __builtin_amdgcn_s_setprio(1);
        #pragma unroll
        for (int ks = 0; ks < 2; ++ks) {
            const int cofs = (32*ks + 8*l4) ^ ((l15 & 7) << 3);
            const f16x8 pa = *(const f16x8*)(pw + l15*64 + cofs);
            acc0 = __builtin_amdgcn_mfma_f32_16x16x32_f16(pa, *(const f16x8*)(Vts + (0*16 + l15)*64 + cofs), acc0, 0,0,0);
            acc1 = __builtin_amdgcn_mfma_f32_16x16x32_f16(pa, *(const f16x8*)(Vts + (1*16 + l15)*64 + cofs), acc1, 0,0,0);
            acc2 = __builtin_amdgcn_mfma_f32_16x16x32_f16(pa, *(const f16x8*)(Vts + (2*16 + l15)*64 + cofs), acc2, 0,0,0);
            acc3 = __builtin_amdgcn_mfma_f32_16x16x32_f16(pa, *(const f16x8*)(Vts + (3*16 + l15)*64 + cofs), acc3, 0,0,0);
        }
        __builtin_amdgcn_s_setprio(0);
    }

    // ---- write partials (unnormalized); acc[dt][e] = O[i=16w+4l4+e][d=16dt+l15]
    float* pacc = (float*)(wsb + OFF_PACC) + (size_t)bx * 8192;
    float* pm   = (float*)(wsb + OFF_PM)  + bx * 128;
    float* pl2  = (float*)(wsb + OFF_PL2) + bx * 128;
    #pragma unroll
    for (int e = 0; e < 4; ++e) {
        const int rowo = (16*w + 4*l4 + e) * 64;
        pacc[rowo +  0 + l15] = acc0[e];
        pacc[rowo + 16 + l15] = acc1[e];
        pacc[rowo + 32 + l15] = acc2[e];
        pacc[rowo + 48 + l15] = acc3[e];
    }
    if (l4 == 0) {
        pm[16*w + l15]  = mi;
        pl2[16*w + l15] = li;
    }
#undef PRELOAD_QV
#undef PRELOAD_MK
}

// ---------------------------------------------------------------------------
// Kernel 3: combine the four j-quarter partials per row and normalize.
// NOTE: partial maxes are in log2 domain -> exp2 weights.
// ---------------------------------------------------------------------------
__global__ __launch_bounds__(256)
void combine(const char* __restrict__ wsb, float* __restrict__ out)
{
    const float* pacc = (const float*)(wsb + OFF_PACC);
    const float* pm   = (const float*)(wsb + OFF_PM);
    const float* pl   = (const float*)(wsb + OFF_PL2);
    const int gid = blockIdx.x * 256 + threadIdx.x;   // 0 .. 262143
    const int row = gid >> 4, q = gid & 15;
    const int b = row >> 12, i = row & 4095;
    const int it = i >> 7, il = i & 127;
    const int pb0 = (b << 7) | (it << 2);
    float m0 = pm[(pb0+0)*128 + il], m1 = pm[(pb0+1)*128 + il];
    float m2 = pm[(pb0+2)*128 + il], m3 = pm[(pb0+3)*128 + il];
    float l0 = pl[(pb0+0)*128 + il], l1 = pl[(pb0+1)*128 + il];
    float l2 = pl[(pb0+2)*128 + il], l3 = pl[(pb0+3)*128 + il];
    const float M = fmaxf(fmaxf(m0, m1), fmaxf(m2, m3));
    const float w0 = exp2f(m0 - M), w1 = exp2f(m1 - M);
    const float w2 = exp2f(m2 - M), w3 = exp2f(m3 - M);
    const float inv = 1.0f / (l0*w0 + l1*w1 + l2*w2 + l3*w3);
    const float4 a0 = *(const float4*)(pacc + (size_t)(pb0+0)*8192 + il*64 + q*4);
    const float4 a1 = *(const float4*)(pacc + (size_t)(pb0+1)*8192 + il*64 + q*4);
    const float4 a2 = *(const float4*)(pacc + (size_t)(pb0+2)*8192 + il*64 + q*4);
    const float4 a3 = *(const float4*)(pacc + (size_t)(pb0+3)*8192 + il*64 + q*4);
    float4 o;
    o.x = (a0.x*w0 + a1.x*w1 + a2.x*w2 + a3.x*w3) * inv;
    o.y = (a0.y*w0 + a1.y*w1 + a2.y*w2 + a3.y*w3) * inv;
    o.z = (a0.z*w0 + a1.z*w1 + a2.z*w2 + a3.z*w3) * inv;
    o.w = (a0.w*w0 + a1.w*w1 + a2.w*w2 + a3.w*w3) * inv;
    *(float4*)(out + (size_t)row*64 + q*4) = o;
}

// ---------------------------------------------------------------------------
extern "C" void kernel_launch(void* const* d_in, const int* in_sizes, int n_in,
                              void* d_out, int out_size, void* d_ws, size_t ws_size,
                              hipStream_t stream) {
    const float* x    = (const float*)d_in[0];
    const int*   mask = (const int*)d_in[1];
    const float* Wk   = (const float*)d_in[2];
    const float* Wq   = (const float*)d_in[3];
    const float* Wv   = (const float*)d_in[4];
    float* out = (float*)d_out;
    char*  wsb = (char*)d_ws;

    hipLaunchKernelGGL(wconv,     dim3(192),  dim3(256), 0, stream, Wk, Wq, Wv, wsb);
    hipLaunchKernelGGL(qkv_mfma,  dim3(512),  dim3(512), 0, stream, x, wsb);
    hipLaunchKernelGGL(flash_f16, dim3(512),  dim3(512), 0, stream, mask, wsb);
    hipLaunchKernelGGL(combine,   dim3(1024), dim3(256), 0, stream, wsb, out);
}

// Round 7
// 156.228 us; speedup vs baseline: 17.8099x; 1.0790x over previous
//
#include <hip/hip_runtime.h>
#include <hip/hip_bf16.h>
#include <math.h>

#define B_ 4
#define S_ 4096
#define H_ 1024
#define D_ 64
#define M_ (B_*S_)            // 16384 rows
#define NEGINF (-1.0e12f)
#define LOG2E 1.4426950408889634f

typedef __attribute__((ext_vector_type(8))) short bf16x8;
typedef __attribute__((ext_vector_type(8))) unsigned short u16x8;
typedef __attribute__((ext_vector_type(8))) _Float16 f16x8;
typedef __attribute__((ext_vector_type(4))) _Float16 f16x4;
typedef __attribute__((ext_vector_type(4))) float f32x4;

// ---- workspace byte offsets ----
#define OFF_WF   0                         // _Float16 [192][1024] W rows (K|Q|V)
#define OFF_KF   786432                    // _Float16 [16384][64]
#define OFF_QF   2883584                   // _Float16 [16384][64]
#define OFF_VTF  4980736                   // _Float16 [64][16384] (V transposed)
#define OFF_PACC 7077888                   // float [512 blocks][128 rows][64]
#define OFF_PM   23855104                  // float [512][128]  (log2-domain max)
#define OFF_PL2  24117248                  // float [512][128]

// ---------------------------------------------------------------------------
// Kernel 0: preconvert W rows (K|Q|V stacked, 192 x 1024) to fp16.
// ---------------------------------------------------------------------------
__global__ __launch_bounds__(256)
void wconv(const float* __restrict__ Wk, const float* __restrict__ Wq,
           const float* __restrict__ Wv, char* __restrict__ wsb)
{
    _Float16* Wf = (_Float16*)(wsb + OFF_WF);
    const int n = blockIdx.x;          // 0..191
    const int t = threadIdx.x;         // 0..255
    const float* src = (n < 64) ? (Wk + (size_t)n*H_)
                     : (n < 128 ? (Wq + (size_t)(n-64)*H_) : (Wv + (size_t)(n-128)*H_));
    float4 v = *(const float4*)(src + t*4);
    f16x4 h;
    h[0] = (_Float16)v.x; h[1] = (_Float16)v.y;
    h[2] = (_Float16)v.z; h[3] = (_Float16)v.w;
    *(f16x4*)(Wf + n*1024 + t*4) = h;
}

// ---------------------------------------------------------------------------
// Kernel 1: QKV projection, single-fp16 MFMA (inputs rounded to fp16 — same
// error order as the fp16 K/Q/V storage downstream). 512 thr = 8 waves
// (2m x 4n). BM=32, BN=192, BK=64, grid=512 -> 2 blocks/CU, 4 waves/SIMD.
// LDS 28 KB (was 56): As [32 m][64 k], Bs [192 n][64 k], XOR-swizzled.
// ---------------------------------------------------------------------------
__global__ __launch_bounds__(512, 4)
void qkv_f16(const float* __restrict__ x, char* __restrict__ wsb)
{
    __shared__ __align__(16) _Float16 As[2048];      // [32 m][64 k] swz
    __shared__ __align__(16) _Float16 Bs[12288];     // [192 n][64 k] swz

    const _Float16* __restrict__ Wf = (const _Float16*)(wsb + OFF_WF);
    _Float16* Kf  = (_Float16*)(wsb + OFF_KF);
    _Float16* Qf  = (_Float16*)(wsb + OFF_QF);
    _Float16* Vtf = (_Float16*)(wsb + OFF_VTF);

    const int tid = threadIdx.x;
    const int w = tid >> 6, l = tid & 63;
    const int l15 = l & 15, l4 = l >> 4;
    const int wm = w & 1, wn = w >> 1;
    const int m0 = blockIdx.x * 32;

    // A staging: one float4 per thread (32x64 fp32 -> fp16)
    const int arow = tid >> 4, ac0 = (tid & 15) * 4;
    const int aoff = arow*64 + (ac0 ^ ((arow & 7) << 3));
    // B staging rows for the 3 chunks
    const int br0 = tid >> 3,          bc0 = (tid & 7) * 8;
    const int br1 = (tid + 512) >> 3;
    const int br2 = (tid + 1024) >> 3;
    const int boff0 = br0*64 + (bc0 ^ ((br0 & 7) << 3));
    const int boff1 = br1*64 + (bc0 ^ ((br1 & 7) << 3));
    const int boff2 = br2*64 + (bc0 ^ ((br2 & 7) << 3));

    float4 xa;
    u16x8 wb0, wb1, wb2;

#define QKV_PREFETCH(K0) do {                                                  \
    xa  = *(const float4*)(x + (size_t)(m0 + arow)*H_ + (K0) + ac0);           \
    wb0 = *(const u16x8*)(Wf + br0*1024 + (K0) + bc0);                         \
    wb1 = *(const u16x8*)(Wf + br1*1024 + (K0) + bc0);                         \
    wb2 = *(const u16x8*)(Wf + br2*1024 + (K0) + bc0);                         \
} while (0)

    QKV_PREFETCH(0);

    f32x4 acc0 = {0.f,0.f,0.f,0.f}, acc1 = {0.f,0.f,0.f,0.f}, acc2 = {0.f,0.f,0.f,0.f};

    for (int k0 = 0; k0 < H_; k0 += 64) {
        __syncthreads();
        {   // commit A (fp32 -> fp16)
            f16x4 av;
            av[0] = (_Float16)xa.x; av[1] = (_Float16)xa.y;
            av[2] = (_Float16)xa.z; av[3] = (_Float16)xa.w;
            *(f16x4*)(As + aoff) = av;
        }
        *(u16x8*)(void*)(Bs + boff0) = wb0;
        *(u16x8*)(void*)(Bs + boff1) = wb1;
        *(u16x8*)(void*)(Bs + boff2) = wb2;
        int kn = (k0 + 64 < H_) ? k0 + 64 : 0;
        QKV_PREFETCH(kn);
        __syncthreads();

        __builtin_amdgcn_s_setprio(1);
        #pragma unroll
        for (int ks = 0; ks < 2; ++ks) {
            const int cofs = (32*ks + 8*l4) ^ ((l15 & 7) << 3);
            const f16x8 ah = *(const f16x8*)(As + (16*wm + l15)*64 + cofs);
            #pragma unroll
            for (int nl = 0; nl < 3; ++nl) {
                const int nrow = (3*wn + nl)*16 + l15;
                const int bo = nrow*64 + ((32*ks + 8*l4) ^ ((nrow & 7) << 3));
                const f16x8 bf = *(const f16x8*)(Bs + bo);
                f32x4* ac = (nl == 0) ? &acc0 : ((nl == 1) ? &acc1 : &acc2);
                *ac = __builtin_amdgcn_mfma_f32_16x16x32_f16(ah, bf, *ac, 0,0,0);
            }
        }
        __builtin_amdgcn_s_setprio(0);
    }

    // epilogue: fp16 outputs; D[m][n]: m = m0+16wm+4*l4+e, n = nt*16+l15
    #pragma unroll
    for (int nl = 0; nl < 3; ++nl) {
        const int nt = 3*wn + nl;
        const int n = nt*16 + l15;
        const f32x4 av = (nl == 0) ? acc0 : ((nl == 1) ? acc1 : acc2);
        if (nt < 4) {
            #pragma unroll
            for (int e = 0; e < 4; ++e)
                Kf[(size_t)(m0 + 16*wm + 4*l4 + e)*64 + n] = (_Float16)av[e];
        } else if (nt < 8) {
            #pragma unroll
            for (int e = 0; e < 4; ++e)
                Qf[(size_t)(m0 + 16*wm + 4*l4 + e)*64 + (n - 64)] = (_Float16)av[e];
        } else {
            f16x4 pk;
            pk[0] = (_Float16)av[0]; pk[1] = (_Float16)av[1];
            pk[2] = (_Float16)av[2]; pk[3] = (_Float16)av[3];
            *(f16x4*)(Vtf + (size_t)(n - 128)*M_ + m0 + 16*wm + 4*l4) = pk;
        }
    }
#undef QKV_PREFETCH
}

// ---------------------------------------------------------------------------
// Kernel 2: flash attention, fp16 MFMA, SWAPPED QK^T (A=Q, B=K) so each lane
// owns one full softmax row (i=l15, 16 j-values in regs). 8 waves/block,
// i-tile 128, KVBLK=64, j-split x4 (grid 512 -> 2 blocks/CU). exp2 domain.
// LDS 32KB: Qs [j][d], Vts [d][j], Ps per-wave [16 i][64 j], all XOR-swizzled.
// (unchanged from R6 — isolating the qkv change this round)
// ---------------------------------------------------------------------------
__global__ __launch_bounds__(512, 4)
void flash_f16(const int* __restrict__ maskp, char* __restrict__ wsb)
{
    __shared__ __align__(16) _Float16 Qs[4096];      // [64 j][64 d] swz
    __shared__ __align__(16) _Float16 Vts[4096];     // [64 d][64 j] swz
    __shared__ __align__(16) _Float16 Ps[8][1024];   // per-wave [16 i][64 j] swz

    const _Float16* __restrict__ Kf  = (const _Float16*)(wsb + OFF_KF);
    const _Float16* __restrict__ Qf  = (const _Float16*)(wsb + OFF_QF);
    const _Float16* __restrict__ Vtf = (const _Float16*)(wsb + OFF_VTF);

    const int tid = threadIdx.x;
    const int w = tid >> 6, l = tid & 63;
    const int l15 = l & 15, l4 = l >> 4;
    const int bx = blockIdx.x;
    const int jh = bx & 3, it = (bx >> 2) & 31, b = bx >> 7;
    const int bS = b * S_;
    const int i0m = bS + it*128;
    const int jbase = jh * 1024;
    const float SC = 0.125f * LOG2E;     // scale folded with log2(e)

    // persistent K fragments (B-operand: lane holds K[i=l15][k=8*l4+e])
    f16x8 kf0, kf1;
    {
        const size_t row = (size_t)(i0m + 16*w + l15) * 64;
        kf0 = *(const f16x8*)(Kf + row + 8*l4);
        kf1 = *(const f16x8*)(Kf + row + 32 + 8*l4);
    }

    const int jr = tid >> 3;             // 0..63
    const int c0 = (tid & 7) * 8;
    const int sidx = jr*64 + (c0 ^ ((jr & 7) << 3));

    u16x8 pq, pv;
    int4 mm0, mm1, mm2, mm3;

#define PRELOAD_QV(JC) do {                                                    \
    pq = *(const u16x8*)(Qf + (size_t)(bS + (JC) + jr)*64 + c0);               \
    pv = *(const u16x8*)(Vtf + (size_t)jr*M_ + bS + (JC) + c0);                \
} while (0)
#define PRELOAD_MK(JC) do {                                                    \
    mm0 = *(const int4*)(maskp + bS + (JC) +  0 + 4*l4);                       \
    mm1 = *(const int4*)(maskp + bS + (JC) + 16 + 4*l4);                       \
    mm2 = *(const int4*)(maskp + bS + (JC) + 32 + 4*l4);                       \
    mm3 = *(const int4*)(maskp + bS + (JC) + 48 + 4*l4);                       \
} while (0)

    PRELOAD_QV(jbase);
    PRELOAD_MK(jbase);

    f32x4 acc0 = {0.f,0.f,0.f,0.f}, acc1 = {0.f,0.f,0.f,0.f};
    f32x4 acc2 = {0.f,0.f,0.f,0.f}, acc3 = {0.f,0.f,0.f,0.f};
    float mi = -INFINITY, li = 0.f;      // state for row i = l15 (dup over l4)

    for (int jc = jbase; jc < jbase + 1024; jc += 64) {
        __syncthreads();                       // prior chunk done reading LDS
        *(u16x8*)(void*)(Qs + sidx)  = pq;
        *(u16x8*)(void*)(Vts + sidx) = pv;
        __syncthreads();                       // staging visible
        int jn = jc + 64; if (jn >= jbase + 1024) jn = jbase;
        PRELOAD_QV(jn);                        // hides under compute

        // ---- QK^T swapped: D[j-row][i-col]; lane -> 16 j for i=l15 ----
        f32x4 sq0 = {0.f,0.f,0.f,0.f}, sq1 = {0.f,0.f,0.f,0.f};
        f32x4 sq2 = {0.f,0.f,0.f,0.f}, sq3 = {0.f,0.f,0.f,0.f};
        __builtin_amdgcn_s_setprio(1);
        #pragma unroll
        for (int ks = 0; ks < 2; ++ks) {
            const f16x8 ka = ks ? kf1 : kf0;
            const int cofs = (32*ks + 8*l4) ^ ((l15 & 7) << 3);
            sq0 = __builtin_amdgcn_mfma_f32_16x16x32_f16(*(const f16x8*)(Qs + (0*16 + l15)*64 + cofs), ka, sq0, 0,0,0);
            sq1 = __builtin_amdgcn_mfma_f32_16x16x32_f16(*(const f16x8*)(Qs + (1*16 + l15)*64 + cofs), ka, sq1, 0,0,0);
            sq2 = __builtin_amdgcn_mfma_f32_16x16x32_f16(*(const f16x8*)(Qs + (2*16 + l15)*64 + cofs), ka, sq2, 0,0,0);
            sq3 = __builtin_amdgcn_mfma_f32_16x16x32_f16(*(const f16x8*)(Qs + (3*16 + l15)*64 + cofs), ka, sq3, 0,0,0);
        }
        __builtin_amdgcn_s_setprio(0);

        // ---- softmax: 16 in-register values, reduce over l4 via 2 shfl ----
        float sv[16];
        sv[ 0] = mm0.x ? sq0[0]*SC : NEGINF;  sv[ 1] = mm0.y ? sq0[1]*SC : NEGINF;
        sv[ 2] = mm0.z ? sq0[2]*SC : NEGINF;  sv[ 3] = mm0.w ? sq0[3]*SC : NEGINF;
        sv[ 4] = mm1.x ? sq1[0]*SC : NEGINF;  sv[ 5] = mm1.y ? sq1[1]*SC : NEGINF;
        sv[ 6] = mm1.z ? sq1[2]*SC : NEGINF;  sv[ 7] = mm1.w ? sq1[3]*SC : NEGINF;
        sv[ 8] = mm2.x ? sq2[0]*SC : NEGINF;  sv[ 9] = mm2.y ? sq2[1]*SC : NEGINF;
        sv[10] = mm2.z ? sq2[2]*SC : NEGINF;  sv[11] = mm2.w ? sq2[3]*SC : NEGINF;
        sv[12] = mm3.x ? sq3[0]*SC : NEGINF;  sv[13] = mm3.y ? sq3[1]*SC : NEGINF;
        sv[14] = mm3.z ? sq3[2]*SC : NEGINF;  sv[15] = mm3.w ? sq3[3]*SC : NEGINF;

        float rm = sv[0];
        #pragma unroll
        for (int k = 1; k < 16; ++k) rm = fmaxf(rm, sv[k]);
        rm = fmaxf(rm, __shfl_xor(rm, 16));
        rm = fmaxf(rm, __shfl_xor(rm, 32));

        if (__ballot(rm > mi + 8.0f)) {        // defer-max (log2 units)
            const float mnew = fmaxf(mi, rm);
            const float alpha = exp2f(mi - mnew);
            li *= alpha; mi = mnew;
            // acc row e is i=4*l4+e; alpha for it lives in lane l15=4*l4+e
            const float a0 = __shfl(alpha, 4*l4 + 0);
            const float a1 = __shfl(alpha, 4*l4 + 1);
            const float a2 = __shfl(alpha, 4*l4 + 2);
            const float a3 = __shfl(alpha, 4*l4 + 3);
            acc0[0]*=a0; acc0[1]*=a1; acc0[2]*=a2; acc0[3]*=a3;
            acc1[0]*=a0; acc1[1]*=a1; acc1[2]*=a2; acc1[3]*=a3;
            acc2[0]*=a0; acc2[1]*=a1; acc2[2]*=a2; acc2[3]*=a3;
            acc3[0]*=a0; acc3[1]*=a1; acc3[2]*=a2; acc3[3]*=a3;
        }

        float p[16];
        float sum = 0.f;
        #pragma unroll
        for (int k = 0; k < 16; ++k) { p[k] = exp2f(sv[k] - mi); sum += p[k]; }
        sum += __shfl_xor(sum, 16);
        sum += __shfl_xor(sum, 32);
        li += sum;

        // ---- stage P (row-major [i=l15][j], b64 packs, wave-private) ----
        _Float16* pw = &Ps[w][0];
        #pragma unroll
        for (int mf = 0; mf < 4; ++mf) {
            f16x4 pk;
            pk[0] = (_Float16)p[4*mf+0]; pk[1] = (_Float16)p[4*mf+1];
            pk[2] = (_Float16)p[4*mf+2]; pk[3] = (_Float16)p[4*mf+3];
            *(f16x4*)(pw + l15*64 + ((16*mf + 4*l4) ^ ((l15 & 7) << 3))) = pk;
        }
        PRELOAD_MK(jn);                        // masks for next chunk (L2 hit)

        // ---- PV: out[i][d] += P[i][j] V[j][d] ----
        __builtin_amdgcn_s_setprio(1);
        #pragma unroll
        for (int ks = 0; ks < 2; ++ks) {
            const int cofs = (32*ks + 8*l4) ^ ((l15 & 7) << 3);
            const f16x8 pa = *(const f16x8*)(pw + l15*64 + cofs);
            acc0 = __builtin_amdgcn_mfma_f32_16x16x32_f16(pa, *(const f16x8*)(Vts + (0*16 + l15)*64 + cofs), acc0, 0,0,0);
            acc1 = __builtin_amdgcn_mfma_f32_16x16x32_f16(pa, *(const f16x8*)(Vts + (1*16 + l15)*64 + cofs), acc1, 0,0,0);
            acc2 = __builtin_amdgcn_mfma_f32_16x16x32_f16(pa, *(const f16x8*)(Vts + (2*16 + l15)*64 + cofs), acc2, 0,0,0);
            acc3 = __builtin_amdgcn_mfma_f32_16x16x32_f16(pa, *(const f16x8*)(Vts + (3*16 + l15)*64 + cofs), acc3, 0,0,0);
        }
        __builtin_amdgcn_s_setprio(0);
    }

    // ---- write partials (unnormalized); acc[dt][e] = O[i=16w+4l4+e][d=16dt+l15]
    float* pacc = (float*)(wsb + OFF_PACC) + (size_t)bx * 8192;
    float* pm   = (float*)(wsb + OFF_PM)  + bx * 128;
    float* pl2  = (float*)(wsb + OFF_PL2) + bx * 128;
    #pragma unroll
    for (int e = 0; e < 4; ++e) {
        const int rowo = (16*w + 4*l4 + e) * 64;
        pacc[rowo +  0 + l15] = acc0[e];
        pacc[rowo + 16 + l15] = acc1[e];
        pacc[rowo + 32 + l15] = acc2[e];
        pacc[rowo + 48 + l15] = acc3[e];
    }
    if (l4 == 0) {
        pm[16*w + l15]  = mi;
        pl2[16*w + l15] = li;
    }
#undef PRELOAD_QV
#undef PRELOAD_MK
}

// ---------------------------------------------------------------------------
// Kernel 3: combine the four j-quarter partials per row and normalize.
// NOTE: partial maxes are in log2 domain -> exp2 weights.
// ---------------------------------------------------------------------------
__global__ __launch_bounds__(256)
void combine(const char* __restrict__ wsb, float* __restrict__ out)
{
    const float* pacc = (const float*)(wsb + OFF_PACC);
    const float* pm   = (const float*)(wsb + OFF_PM);
    const float* pl   = (const float*)(wsb + OFF_PL2);
    const int gid = blockIdx.x * 256 + threadIdx.x;   // 0 .. 262143
    const int row = gid >> 4, q = gid & 15;
    const int b = row >> 12, i = row & 4095;
    const int it = i >> 7, il = i & 127;
    const int pb0 = (b << 7) | (it << 2);
    float m0 = pm[(pb0+0)*128 + il], m1 = pm[(pb0+1)*128 + il];
    float m2 = pm[(pb0+2)*128 + il], m3 = pm[(pb0+3)*128 + il];
    float l0 = pl[(pb0+0)*128 + il], l1 = pl[(pb0+1)*128 + il];
    float l2 = pl[(pb0+2)*128 + il], l3 = pl[(pb0+3)*128 + il];
    const float M = fmaxf(fmaxf(m0, m1), fmaxf(m2, m3));
    const float w0 = exp2f(m0 - M), w1 = exp2f(m1 - M);
    const float w2 = exp2f(m2 - M), w3 = exp2f(m3 - M);
    const float inv = 1.0f / (l0*w0 + l1*w1 + l2*w2 + l3*w3);
    const float4 a0 = *(const float4*)(pacc + (size_t)(pb0+0)*8192 + il*64 + q*4);
    const float4 a1 = *(const float4*)(pacc + (size_t)(pb0+1)*8192 + il*64 + q*4);
    const float4 a2 = *(const float4*)(pacc + (size_t)(pb0+2)*8192 + il*64 + q*4);
    const float4 a3 = *(const float4*)(pacc + (size_t)(pb0+3)*8192 + il*64 + q*4);
    float4 o;
    o.x = (a0.x*w0 + a1.x*w1 + a2.x*w2 + a3.x*w3) * inv;
    o.y = (a0.y*w0 + a1.y*w1 + a2.y*w2 + a3.y*w3) * inv;
    o.z = (a0.z*w0 + a1.z*w1 + a2.z*w2 + a3.z*w3) * inv;
    o.w = (a0.w*w0 + a1.w*w1 + a2.w*w2 + a3.w*w3) * inv;
    *(float4*)(out + (size_t)row*64 + q*4) = o;
}

// ---------------------------------------------------------------------------
extern "C" void kernel_launch(void* const* d_in, const int* in_sizes, int n_in,
                              void* d_out, int out_size, void* d_ws, size_t ws_size,
                              hipStream_t stream) {
    const float* x    = (const float*)d_in[0];
    const int*   mask = (const int*)d_in[1];
    const float* Wk   = (const float*)d_in[2];
    const float* Wq   = (const float*)d_in[3];
    const float* Wv   = (const float*)d_in[4];
    float* out = (float*)d_out;
    char*  wsb = (char*)d_ws;

    hipLaunchKernelGGL(wconv,     dim3(192),  dim3(256), 0, stream, Wk, Wq, Wv, wsb);
    hipLaunchKernelGGL(qkv_f16,   dim3(512),  dim3(512), 0, stream, x, wsb);
    hipLaunchKernelGGL(flash_f16, dim3(512),  dim3(512), 0, stream, mask, wsb);
    hipLaunchKernelGGL(combine,   dim3(1024), dim3(256), 0, stream, wsb, out);
}